// Round 1
// baseline (1794.973 us; speedup 1.0000x reference)
//
#include <hip/hip_runtime.h>
#include <hip/hip_bf16.h>

#define NNODES 50000

__device__ __forceinline__ unsigned fenc(float f){
  unsigned u = __float_as_uint(f);
  return (u & 0x80000000u) ? ~u : (u | 0x80000000u);
}
__device__ __forceinline__ float fdec(unsigned u){
  unsigned b = (u & 0x80000000u) ? (u & 0x7fffffffu) : ~u;
  return __uint_as_float(b);
}

// Y[nrows, NCOL] = X[nrows, K] @ W[K, NCOL], 256 threads/block, ROWS rows per block.
template<int K, int NCOL, int ROWS>
__global__ __launch_bounds__(256)
void gemm_k(const float* __restrict__ X, const float* __restrict__ W,
            float* __restrict__ Y, int nrows){
  constexpr int G = 256 / NCOL;     // thread row-groups
  constexpr int RPT = ROWS / G;     // rows per thread
  __shared__ float xs[ROWS][K + 4]; // +4 pad: row stride 260/132 words -> banks differ by 4
  const int row0 = blockIdx.x * ROWS;
  const int tid = threadIdx.x;
  for (int i = tid * 4; i < ROWS * K; i += 1024){
    int r = i / K, k = i - r * K;
    int gr = row0 + r;
    float4 v = make_float4(0.f, 0.f, 0.f, 0.f);
    if (gr < nrows) v = *(const float4*)(X + (size_t)gr * K + k);
    *(float4*)&xs[r][k] = v;
  }
  __syncthreads();
  const int j = tid % NCOL;
  const int g = tid / NCOL;
  float acc[RPT];
  #pragma unroll
  for (int r = 0; r < RPT; r++) acc[r] = 0.f;
  for (int k = 0; k < K; k += 4){
    float w0 = W[(k + 0) * NCOL + j];
    float w1 = W[(k + 1) * NCOL + j];
    float w2 = W[(k + 2) * NCOL + j];
    float w3 = W[(k + 3) * NCOL + j];
    #pragma unroll
    for (int r = 0; r < RPT; r++){
      float4 xv = *(const float4*)&xs[g + r * G][k];
      acc[r] = fmaf(xv.x, w0, acc[r]);
      acc[r] = fmaf(xv.y, w1, acc[r]);
      acc[r] = fmaf(xv.z, w2, acc[r]);
      acc[r] = fmaf(xv.w, w3, acc[r]);
    }
  }
  #pragma unroll
  for (int r = 0; r < RPT; r++){
    int gr = row0 + g + r * G;
    if (gr < nrows) Y[(size_t)gr * NCOL + j] = acc[r];
  }
}

// alpha_src/alpha_dst: one thread per (node, head); h laid out [n][H][64]
template<int H>
__global__ __launch_bounds__(256)
void alpha_k(const float* __restrict__ h, const float* __restrict__ a_s,
             const float* __restrict__ a_d, float* __restrict__ os,
             float* __restrict__ od, int n){
  int i = blockIdx.x * 256 + threadIdx.x;
  if (i >= n * H) return;
  int hh = i % H;
  const float* hp  = h + (size_t)i * 64;
  const float* asp = a_s + hh * 64;
  const float* adp = a_d + hh * 64;
  float s1 = 0.f, s2 = 0.f;
  #pragma unroll 8
  for (int d = 0; d < 64; d++){
    float hv = hp[d];
    s1 = fmaf(hv, asp[d], s1);
    s2 = fmaf(hv, adp[d], s2);
  }
  os[i] = s1; od[i] = s2;
}

template<int H>
__global__ __launch_bounds__(256)
void edge_max_k(const int* __restrict__ ei, int E0, int Etot,
                const float* __restrict__ as, const float* __restrict__ ad,
                unsigned* __restrict__ menc){
  int e = blockIdx.x * 256 + threadIdx.x;
  if (e >= Etot) return;
  int s, d;
  if (e < E0){ s = ei[e]; d = ei[E0 + e]; } else { s = d = e - E0; }
  #pragma unroll
  for (int h = 0; h < H; h++){
    float v = as[s * H + h] + ad[d * H + h];
    v = v > 0.f ? v : 0.2f * v;
    atomicMax(&menc[d * H + h], fenc(v));
  }
}

__global__ __launch_bounds__(256)
void decode_k(unsigned* __restrict__ m, int n){
  int i = blockIdx.x * 256 + threadIdx.x;
  if (i < n){ float f = fdec(m[i]); ((float*)m)[i] = f; }
}

template<int H>
__global__ __launch_bounds__(256)
void edge_sum_k(const int* __restrict__ ei, int E0, int Etot,
                const float* __restrict__ as, const float* __restrict__ ad,
                const float* __restrict__ m, float* __restrict__ den){
  int e = blockIdx.x * 256 + threadIdx.x;
  if (e >= Etot) return;
  int s, d;
  if (e < E0){ s = ei[e]; d = ei[E0 + e]; } else { s = d = e - E0; }
  #pragma unroll
  for (int h = 0; h < H; h++){
    float v = as[s * H + h] + ad[d * H + h];
    v = v > 0.f ? v : 0.2f * v;
    atomicAdd(&den[d * H + h], __expf(v - m[d * H + h]));
  }
}

// 64 lanes per edge; out[(dst*H+h)*64 + lane] += h[(src*H+h)*64 + lane] * alpha
template<int H>
__global__ __launch_bounds__(256)
void edge_scatter_k(const int* __restrict__ ei, int E0, int Etot,
                    const float* __restrict__ as, const float* __restrict__ ad,
                    const float* __restrict__ m, const float* __restrict__ den,
                    const float* __restrict__ hsrc, float* __restrict__ out){
  int t = blockIdx.x * 256 + threadIdx.x;
  int lane = t & 63;
  int e = t >> 6;
  if (e >= Etot) return;
  int s, d;
  if (e < E0){ s = ei[e]; d = ei[E0 + e]; } else { s = d = e - E0; }
  #pragma unroll
  for (int h = 0; h < H; h++){
    float v = as[s * H + h] + ad[d * H + h];
    v = v > 0.f ? v : 0.2f * v;
    float alpha = __expf(v - m[d * H + h]) / (den[d * H + h] + 1e-16f);
    atomicAdd(&out[(size_t)(d * H + h) * 64 + lane],
              hsrc[(size_t)(s * H + h) * 64 + lane] * alpha);
  }
}

__global__ __launch_bounds__(256)
void relu_bias1_k(float* __restrict__ buf, const float* __restrict__ b, int total){
  int i = blockIdx.x * 256 + threadIdx.x;
  if (i >= total) return;
  float v = buf[i] + b[i & 255];
  buf[i] = v > 0.f ? v : 0.f;
}

__global__ __launch_bounds__(256)
void bias2_k(float* __restrict__ out, const float* __restrict__ bmu,
             const float* __restrict__ bls, int half){
  int i = blockIdx.x * 256 + threadIdx.x;
  if (i < half) out[i] += bmu[i & 63];
  else if (i < 2 * half) out[i] += bls[i & 63];
}

extern "C" void kernel_launch(void* const* d_in, const int* in_sizes, int n_in,
                              void* d_out, int out_size, void* d_ws, size_t ws_size,
                              hipStream_t stream){
  const float* x    = (const float*)d_in[0];
  const int*   ei   = (const int*)d_in[1];
  const float* W1   = (const float*)d_in[2];
  const float* aS1  = (const float*)d_in[3];
  const float* aD1  = (const float*)d_in[4];
  const float* b1   = (const float*)d_in[5];
  const float* Wmu  = (const float*)d_in[6];
  const float* aSmu = (const float*)d_in[7];
  const float* aDmu = (const float*)d_in[8];
  const float* bmu  = (const float*)d_in[9];
  const float* Wls  = (const float*)d_in[10];
  const float* aSls = (const float*)d_in[11];
  const float* aDls = (const float*)d_in[12];
  const float* bls  = (const float*)d_in[13];

  const int N    = NNODES;
  const int E0   = in_sizes[1] / 2;
  const int Etot = E0 + N;

  float* ws   = (float*)d_ws;
  float* hbuf = ws;                    // 12.8M floats: h1, later h2_mu / h2_ls
  float* bbuf = ws + 12800000;         // 12.8M floats: layer-1 accum -> h
  float* as1  = ws + 25600000;         // 200K
  float* ad1  = as1 + 200000;
  float* m1   = ad1 + 200000;          // unsigned enc, decoded in place
  float* den1 = m1  + 200000;
  float* as2m = den1 + 200000;         // 50K each below
  float* ad2m = as2m + 50000;
  float* m2m  = ad2m + 50000;
  float* den2m= m2m  + 50000;
  float* as2l = den2m + 50000;
  float* ad2l = as2l + 50000;
  float* m2l  = ad2l + 50000;
  float* den2l= m2l  + 50000;

  float* h2mu = hbuf;                  // reuse after layer 1 done
  float* h2ls = hbuf + 3200000;
  float* outmu = (float*)d_out;
  float* outls = (float*)d_out + 3200000;

  // zero all accumulators (ws/out are poisoned by the harness)
  hipMemsetAsync(bbuf, 0, 12800000 * sizeof(float), stream);
  hipMemsetAsync(m1,   0, 200000 * sizeof(float), stream);
  hipMemsetAsync(den1, 0, 200000 * sizeof(float), stream);
  hipMemsetAsync(m2m,  0, 50000 * sizeof(float), stream);
  hipMemsetAsync(den2m,0, 50000 * sizeof(float), stream);
  hipMemsetAsync(m2l,  0, 50000 * sizeof(float), stream);
  hipMemsetAsync(den2l,0, 50000 * sizeof(float), stream);
  hipMemsetAsync(d_out,0, (size_t)out_size * sizeof(float), stream);

  const int egrid = (Etot + 255) / 256;
  const int sgrid = (Etot * 64 + 255) / 256;

  // ---- layer 1: GATConv(128 -> 4 heads x 64, concat) ----
  gemm_k<128, 256, 32><<<(N + 31) / 32, 256, 0, stream>>>(x, W1, hbuf, N);
  alpha_k<4><<<(N * 4 + 255) / 256, 256, 0, stream>>>(hbuf, aS1, aD1, as1, ad1, N);
  edge_max_k<4><<<egrid, 256, 0, stream>>>(ei, E0, Etot, as1, ad1, (unsigned*)m1);
  decode_k<<<(N * 4 + 255) / 256, 256, 0, stream>>>((unsigned*)m1, N * 4);
  edge_sum_k<4><<<egrid, 256, 0, stream>>>(ei, E0, Etot, as1, ad1, m1, den1);
  edge_scatter_k<4><<<sgrid, 256, 0, stream>>>(ei, E0, Etot, as1, ad1, m1, den1, hbuf, bbuf);
  relu_bias1_k<<<(N * 256 + 255) / 256, 256, 0, stream>>>(bbuf, b1, N * 256);

  // ---- layer mu: GATConv(256 -> 1 head x 64) ----
  gemm_k<256, 64, 32><<<(N + 31) / 32, 256, 0, stream>>>(bbuf, Wmu, h2mu, N);
  alpha_k<1><<<(N + 255) / 256, 256, 0, stream>>>(h2mu, aSmu, aDmu, as2m, ad2m, N);
  edge_max_k<1><<<egrid, 256, 0, stream>>>(ei, E0, Etot, as2m, ad2m, (unsigned*)m2m);
  decode_k<<<(N + 255) / 256, 256, 0, stream>>>((unsigned*)m2m, N);
  edge_sum_k<1><<<egrid, 256, 0, stream>>>(ei, E0, Etot, as2m, ad2m, m2m, den2m);
  edge_scatter_k<1><<<sgrid, 256, 0, stream>>>(ei, E0, Etot, as2m, ad2m, m2m, den2m, h2mu, outmu);

  // ---- layer logstd ----
  gemm_k<256, 64, 32><<<(N + 31) / 32, 256, 0, stream>>>(bbuf, Wls, h2ls, N);
  alpha_k<1><<<(N + 255) / 256, 256, 0, stream>>>(h2ls, aSls, aDls, as2l, ad2l, N);
  edge_max_k<1><<<egrid, 256, 0, stream>>>(ei, E0, Etot, as2l, ad2l, (unsigned*)m2l);
  decode_k<<<(N + 255) / 256, 256, 0, stream>>>((unsigned*)m2l, N);
  edge_sum_k<1><<<egrid, 256, 0, stream>>>(ei, E0, Etot, as2l, ad2l, m2l, den2l);
  edge_scatter_k<1><<<sgrid, 256, 0, stream>>>(ei, E0, Etot, as2l, ad2l, m2l, den2l, h2ls, outls);

  // final bias add
  bias2_k<<<(2 * 3200000 + 255) / 256, 256, 0, stream>>>(outmu, bmu, bls, 3200000);
}

// Round 2
// 557.696 us; speedup vs baseline: 3.2186x; 3.2186x over previous
//
#include <hip/hip_runtime.h>
#include <hip/hip_bf16.h>

#define NNODES 50000

// ---------------- GEMM: Y[nrows,NCOL] = X[nrows,K] @ W[K,NCOL] ----------------
template<int K, int NCOL, int ROWS>
__global__ __launch_bounds__(256)
void gemm_k(const float* __restrict__ X, const float* __restrict__ W,
            float* __restrict__ Y, int nrows){
  constexpr int G = 256 / NCOL;
  constexpr int RPT = ROWS / G;
  __shared__ float xs[ROWS][K + 4];
  const int row0 = blockIdx.x * ROWS;
  const int tid = threadIdx.x;
  for (int i = tid * 4; i < ROWS * K; i += 1024){
    int r = i / K, k = i - r * K;
    int gr = row0 + r;
    float4 v = make_float4(0.f, 0.f, 0.f, 0.f);
    if (gr < nrows) v = *(const float4*)(X + (size_t)gr * K + k);
    *(float4*)&xs[r][k] = v;
  }
  __syncthreads();
  const int j = tid % NCOL;
  const int g = tid / NCOL;
  float acc[RPT];
  #pragma unroll
  for (int r = 0; r < RPT; r++) acc[r] = 0.f;
  for (int k = 0; k < K; k += 4){
    float w0 = W[(k + 0) * NCOL + j];
    float w1 = W[(k + 1) * NCOL + j];
    float w2 = W[(k + 2) * NCOL + j];
    float w3 = W[(k + 3) * NCOL + j];
    #pragma unroll
    for (int r = 0; r < RPT; r++){
      float4 xv = *(const float4*)&xs[g + r * G][k];
      acc[r] = fmaf(xv.x, w0, acc[r]);
      acc[r] = fmaf(xv.y, w1, acc[r]);
      acc[r] = fmaf(xv.z, w2, acc[r]);
      acc[r] = fmaf(xv.w, w3, acc[r]);
    }
  }
  #pragma unroll
  for (int r = 0; r < RPT; r++){
    int gr = row0 + g + r * G;
    if (gr < nrows) Y[(size_t)gr * NCOL + j] = acc[r];
  }
}

// ---------------- per-node attention logits ----------------
template<int H>
__global__ __launch_bounds__(256)
void alpha_k(const float* __restrict__ h, const float* __restrict__ a_s,
             const float* __restrict__ a_d, float* __restrict__ os,
             float* __restrict__ od, int n){
  int i = blockIdx.x * 256 + threadIdx.x;
  if (i >= n * H) return;
  int hh = i % H;
  const float* hp  = h + (size_t)i * 64;
  const float* asp = a_s + hh * 64;
  const float* adp = a_d + hh * 64;
  float s1 = 0.f, s2 = 0.f;
  #pragma unroll 8
  for (int d = 0; d < 64; d++){
    float hv = hp[d];
    s1 = fmaf(hv, asp[d], s1);
    s2 = fmaf(hv, adp[d], s2);
  }
  os[i] = s1; od[i] = s2;
}

// ---------------- CSR build ----------------
__global__ __launch_bounds__(256)
void hist_k(const int* __restrict__ ei, int E0, int Etot, int* __restrict__ cnt){
  int e = blockIdx.x * 256 + threadIdx.x;
  if (e >= Etot) return;
  int d = (e < E0) ? ei[E0 + e] : e - E0;
  atomicAdd(&cnt[d], 1);
}

__global__ __launch_bounds__(1024)
void scanA_k(const int* __restrict__ cnt, int* __restrict__ offs,
             int* __restrict__ bsums, int n){
  __shared__ int buf[1024];
  int tid = threadIdx.x;
  int i = blockIdx.x * 1024 + tid;
  int v = (i < n) ? cnt[i] : 0;
  buf[tid] = v; __syncthreads();
  int acc = v;
  for (int off = 1; off < 1024; off <<= 1){
    int t = (tid >= off) ? buf[tid - off] : 0;
    __syncthreads();
    acc += t; buf[tid] = acc;
    __syncthreads();
  }
  if (i < n) offs[i] = acc - v;          // exclusive within block
  if (tid == 1023) bsums[blockIdx.x] = acc;
}

__global__ void scanB_k(int* __restrict__ bsums, int nb){
  if (threadIdx.x == 0 && blockIdx.x == 0){
    int run = 0;
    for (int i = 0; i < nb; i++){ int t = bsums[i]; bsums[i] = run; run += t; }
  }
}

__global__ __launch_bounds__(256)
void scanC_k(int* __restrict__ offs, const int* __restrict__ bsums,
             int* __restrict__ cursor, int n, int total){
  int i = blockIdx.x * 256 + threadIdx.x;
  if (i < n){
    int v = offs[i] + bsums[i >> 10];
    offs[i] = v;
    cursor[i] = v;
  }
  if (i == 0) offs[n] = total;
}

__global__ __launch_bounds__(256)
void sort_k(const int* __restrict__ ei, int E0, int Etot,
            int* __restrict__ cursor, int* __restrict__ srcs){
  int e = blockIdx.x * 256 + threadIdx.x;
  if (e >= Etot) return;
  int s, d;
  if (e < E0){ s = ei[e]; d = ei[E0 + e]; } else { s = d = e - E0; }
  int pos = atomicAdd(&cursor[d], 1);
  srcs[pos] = s;
}

// ---------------- fused GAT aggregation, layer 1 (H=4, D=64) ----------------
// block = 256 threads = 4 waves; wave w handles head w of node blockIdx.x
__global__ __launch_bounds__(256)
void gat_aggr1_k(const int* __restrict__ offs, const int* __restrict__ srcs,
                 const float* __restrict__ h, const float* __restrict__ as,
                 const float* __restrict__ ad, const float* __restrict__ b,
                 float* __restrict__ out, int n){
  int node = blockIdx.x;
  if (node >= n) return;
  int hh   = threadIdx.x >> 6;
  int lane = threadIdx.x & 63;
  int beg = offs[node], end = offs[node + 1];
  float adv = ad[node * 4 + hh];
  // pass 1: wave-parallel max
  float mx = -1e30f;
  for (int j = beg + lane; j < end; j += 64){
    int s = srcs[j];
    float e = as[s * 4 + hh] + adv;
    e = e > 0.f ? e : 0.2f * e;
    mx = fmaxf(mx, e);
  }
  #pragma unroll
  for (int o = 32; o > 0; o >>= 1) mx = fmaxf(mx, __shfl_xor(mx, o));
  // pass 2: wave-parallel denom
  float den = 0.f;
  for (int j = beg + lane; j < end; j += 64){
    int s = srcs[j];
    float e = as[s * 4 + hh] + adv;
    e = e > 0.f ? e : 0.2f * e;
    den += __expf(e - mx);
  }
  #pragma unroll
  for (int o = 32; o > 0; o >>= 1) den += __shfl_xor(den, o);
  float inv = 1.f / (den + 1e-16f);
  // pass 3: weighted gather-accumulate (lane = feature dim)
  float acc = 0.f;
  int j = beg;
  for (; j + 1 < end; j += 2){
    int s0 = srcs[j], s1 = srcs[j + 1];
    float e0 = as[s0 * 4 + hh] + adv; e0 = e0 > 0.f ? e0 : 0.2f * e0;
    float e1 = as[s1 * 4 + hh] + adv; e1 = e1 > 0.f ? e1 : 0.2f * e1;
    float a0 = __expf(e0 - mx) * inv;
    float a1 = __expf(e1 - mx) * inv;
    float h0 = h[(size_t)s0 * 256 + hh * 64 + lane];
    float h1v = h[(size_t)s1 * 256 + hh * 64 + lane];
    acc = fmaf(h0, a0, acc);
    acc = fmaf(h1v, a1, acc);
  }
  if (j < end){
    int s0 = srcs[j];
    float e0 = as[s0 * 4 + hh] + adv; e0 = e0 > 0.f ? e0 : 0.2f * e0;
    acc = fmaf(h[(size_t)s0 * 256 + hh * 64 + lane], __expf(e0 - mx) * inv, acc);
  }
  float v = acc + b[hh * 64 + lane];
  out[(size_t)node * 256 + hh * 64 + lane] = v > 0.f ? v : 0.f;  // fused bias+ReLU
}

// ---------------- fused GAT aggregation, mu & logstd (H=1, D=64) ----------------
// block = 128 threads = 2 waves; wave 0 -> mu, wave 1 -> logstd
__global__ __launch_bounds__(128)
void gat_aggr2_k(const int* __restrict__ offs, const int* __restrict__ srcs,
                 const float* __restrict__ hmu, const float* __restrict__ hls,
                 const float* __restrict__ asMu, const float* __restrict__ adMu,
                 const float* __restrict__ asLs, const float* __restrict__ adLs,
                 const float* __restrict__ bmu, const float* __restrict__ bls,
                 float* __restrict__ outmu, float* __restrict__ outls, int n){
  int node = blockIdx.x;
  if (node >= n) return;
  int wave = threadIdx.x >> 6;
  int lane = threadIdx.x & 63;
  const float* as = wave ? asLs : asMu;
  const float* adp = wave ? adLs : adMu;
  const float* h  = wave ? hls : hmu;
  const float* bb = wave ? bls : bmu;
  float* out = wave ? outls : outmu;
  int beg = offs[node], end = offs[node + 1];
  float adv = adp[node];
  float mx = -1e30f;
  for (int j = beg + lane; j < end; j += 64){
    float e = as[srcs[j]] + adv;
    e = e > 0.f ? e : 0.2f * e;
    mx = fmaxf(mx, e);
  }
  #pragma unroll
  for (int o = 32; o > 0; o >>= 1) mx = fmaxf(mx, __shfl_xor(mx, o));
  float den = 0.f;
  for (int j = beg + lane; j < end; j += 64){
    float e = as[srcs[j]] + adv;
    e = e > 0.f ? e : 0.2f * e;
    den += __expf(e - mx);
  }
  #pragma unroll
  for (int o = 32; o > 0; o >>= 1) den += __shfl_xor(den, o);
  float inv = 1.f / (den + 1e-16f);
  float acc = 0.f;
  int j = beg;
  for (; j + 1 < end; j += 2){
    int s0 = srcs[j], s1 = srcs[j + 1];
    float e0 = as[s0] + adv; e0 = e0 > 0.f ? e0 : 0.2f * e0;
    float e1 = as[s1] + adv; e1 = e1 > 0.f ? e1 : 0.2f * e1;
    float a0 = __expf(e0 - mx) * inv;
    float a1 = __expf(e1 - mx) * inv;
    acc = fmaf(h[(size_t)s0 * 64 + lane], a0, acc);
    acc = fmaf(h[(size_t)s1 * 64 + lane], a1, acc);
  }
  if (j < end){
    int s0 = srcs[j];
    float e0 = as[s0] + adv; e0 = e0 > 0.f ? e0 : 0.2f * e0;
    acc = fmaf(h[(size_t)s0 * 64 + lane], __expf(e0 - mx) * inv, acc);
  }
  out[(size_t)node * 64 + lane] = acc + bb[lane];  // fused bias
}

extern "C" void kernel_launch(void* const* d_in, const int* in_sizes, int n_in,
                              void* d_out, int out_size, void* d_ws, size_t ws_size,
                              hipStream_t stream){
  const float* x    = (const float*)d_in[0];
  const int*   ei   = (const int*)d_in[1];
  const float* W1   = (const float*)d_in[2];
  const float* aS1  = (const float*)d_in[3];
  const float* aD1  = (const float*)d_in[4];
  const float* b1   = (const float*)d_in[5];
  const float* Wmu  = (const float*)d_in[6];
  const float* aSmu = (const float*)d_in[7];
  const float* aDmu = (const float*)d_in[8];
  const float* bmu  = (const float*)d_in[9];
  const float* Wls  = (const float*)d_in[10];
  const float* aSls = (const float*)d_in[11];
  const float* aDls = (const float*)d_in[12];
  const float* bls  = (const float*)d_in[13];

  const int N    = NNODES;
  const int E0   = in_sizes[1] / 2;
  const int Etot = E0 + N;

  // ---- workspace layout ----
  float* ws   = (float*)d_ws;
  float* hbuf = ws;                    // 12.8M floats: h1; later h2mu/h2ls
  float* bbuf = ws + 12800000;         // 12.8M floats: layer-1 output (relu'd)
  float* as1  = ws + 25600000;         // 200K floats
  float* ad1  = ws + 25800000;         // 200K floats
  // CSR-build-phase overlays (dead before as1/ad1 are written):
  int* cnt    = (int*)ad1;             // 50000 ints
  int* cursor = cnt + 50000;           // 50000 ints
  // layer-2 alpha overlays (as1 dead after layer-1 aggregation):
  float* as2m = as1;
  float* ad2m = as1 + 50000;
  float* as2l = as1 + 100000;
  float* ad2l = as1 + 150000;
  // persistent CSR:
  int* offs  = (int*)(ws + 26000000);  // 50001 ints
  int* srcs  = offs + 50001;           // 850000 ints
  int* bsums = srcs + 850000;          // 64 ints

  float* h2mu = hbuf;                  // reuse after layer-1 aggregation
  float* h2ls = hbuf + 3200000;
  float* outmu = (float*)d_out;
  float* outls = (float*)d_out + 3200000;

  const int egrid = (Etot + 255) / 256;

  // ---- CSR build (shared by all 3 convs) ----
  hipMemsetAsync(cnt, 0, 50000 * sizeof(int), stream);
  hist_k<<<egrid, 256, 0, stream>>>(ei, E0, Etot, cnt);
  scanA_k<<<(N + 1023) / 1024, 1024, 0, stream>>>(cnt, offs, bsums, N);
  scanB_k<<<1, 64, 0, stream>>>(bsums, (N + 1023) / 1024);
  scanC_k<<<(N + 256) / 256, 256, 0, stream>>>(offs, bsums, cursor, N, Etot);
  sort_k<<<egrid, 256, 0, stream>>>(ei, E0, Etot, cursor, srcs);

  // ---- layer 1: GATConv(128 -> 4 heads x 64, concat) + bias + ReLU ----
  gemm_k<128, 256, 32><<<(N + 31) / 32, 256, 0, stream>>>(x, W1, hbuf, N);
  alpha_k<4><<<(N * 4 + 255) / 256, 256, 0, stream>>>(hbuf, aS1, aD1, as1, ad1, N);
  gat_aggr1_k<<<N, 256, 0, stream>>>(offs, srcs, hbuf, as1, ad1, b1, bbuf, N);

  // ---- layers mu & logstd: GATConv(256 -> 1 head x 64) + bias ----
  gemm_k<256, 64, 32><<<(N + 31) / 32, 256, 0, stream>>>(bbuf, Wmu, h2mu, N);
  gemm_k<256, 64, 32><<<(N + 31) / 32, 256, 0, stream>>>(bbuf, Wls, h2ls, N);
  alpha_k<1><<<(N + 255) / 256, 256, 0, stream>>>(h2mu, aSmu, aDmu, as2m, ad2m, N);
  alpha_k<1><<<(N + 255) / 256, 256, 0, stream>>>(h2ls, aSls, aDls, as2l, ad2l, N);
  gat_aggr2_k<<<N, 128, 0, stream>>>(offs, srcs, h2mu, h2ls,
                                     as2m, ad2m, as2l, ad2l,
                                     bmu, bls, outmu, outls, N);
}

// Round 3
// 520.206 us; speedup vs baseline: 3.4505x; 1.0721x over previous
//
#include <hip/hip_runtime.h>
#include <hip/hip_bf16.h>

#define NNODES 50000
typedef __hip_bfloat16 bf16;

// ---------------- GEMM: Ybf[nrows,NCOL] = bf16( X[nrows,K] @ W[K,NCOL] ) ----------------
template<int K, int NCOL, int ROWS>
__global__ __launch_bounds__(256)
void gemm_k(const float* __restrict__ X, const float* __restrict__ W,
            bf16* __restrict__ Ybf, int nrows){
  constexpr int G = 256 / NCOL;
  constexpr int RPT = ROWS / G;
  __shared__ float xs[ROWS][K + 4];
  const int row0 = blockIdx.x * ROWS;
  const int tid = threadIdx.x;
  for (int i = tid * 4; i < ROWS * K; i += 1024){
    int r = i / K, k = i - r * K;
    int gr = row0 + r;
    float4 v = make_float4(0.f, 0.f, 0.f, 0.f);
    if (gr < nrows) v = *(const float4*)(X + (size_t)gr * K + k);
    *(float4*)&xs[r][k] = v;
  }
  __syncthreads();
  const int j = tid % NCOL;
  const int g = tid / NCOL;
  float acc[RPT];
  #pragma unroll
  for (int r = 0; r < RPT; r++) acc[r] = 0.f;
  for (int k = 0; k < K; k += 4){
    float w0 = W[(k + 0) * NCOL + j];
    float w1 = W[(k + 1) * NCOL + j];
    float w2 = W[(k + 2) * NCOL + j];
    float w3 = W[(k + 3) * NCOL + j];
    #pragma unroll
    for (int r = 0; r < RPT; r++){
      float4 xv = *(const float4*)&xs[g + r * G][k];
      acc[r] = fmaf(xv.x, w0, acc[r]);
      acc[r] = fmaf(xv.y, w1, acc[r]);
      acc[r] = fmaf(xv.z, w2, acc[r]);
      acc[r] = fmaf(xv.w, w3, acc[r]);
    }
  }
  #pragma unroll
  for (int r = 0; r < RPT; r++){
    int gr = row0 + g + r * G;
    if (gr < nrows) Ybf[(size_t)gr * NCOL + j] = __float2bfloat16(acc[r]);
  }
}

// ---------------- per-node attention logits from bf16 h ----------------
template<int H>
__global__ __launch_bounds__(256)
void alpha_k(const bf16* __restrict__ h, const float* __restrict__ a_s,
             const float* __restrict__ a_d, float* __restrict__ os,
             float* __restrict__ od, int n){
  int i = blockIdx.x * 256 + threadIdx.x;
  if (i >= n * H) return;
  int hh = i % H;
  const uint4* hp  = (const uint4*)(h + (size_t)i * 64);
  const float* asp = a_s + hh * 64;
  const float* adp = a_d + hh * 64;
  float s1 = 0.f, s2 = 0.f;
  #pragma unroll
  for (int q = 0; q < 8; q++){
    uint4 v = hp[q];
    unsigned w[4] = {v.x, v.y, v.z, v.w};
    #pragma unroll
    for (int p = 0; p < 4; p++){
      float lo = __uint_as_float(w[p] << 16);
      float hi = __uint_as_float(w[p] & 0xffff0000u);
      int d = q * 8 + p * 2;
      s1 = fmaf(lo, asp[d], s1);     s2 = fmaf(lo, adp[d], s2);
      s1 = fmaf(hi, asp[d + 1], s1); s2 = fmaf(hi, adp[d + 1], s2);
    }
  }
  os[i] = s1; od[i] = s2;
}

// ---------------- CSR build ----------------
__global__ __launch_bounds__(256)
void hist_k(const int* __restrict__ ei, int E0, int Etot, int* __restrict__ cnt){
  int e = blockIdx.x * 256 + threadIdx.x;
  if (e >= Etot) return;
  int d = (e < E0) ? ei[E0 + e] : e - E0;
  atomicAdd(&cnt[d], 1);
}

__global__ __launch_bounds__(1024)
void scanA_k(const int* __restrict__ cnt, int* __restrict__ offs,
             int* __restrict__ bsums, int n){
  __shared__ int buf[1024];
  int tid = threadIdx.x;
  int i = blockIdx.x * 1024 + tid;
  int v = (i < n) ? cnt[i] : 0;
  buf[tid] = v; __syncthreads();
  int acc = v;
  for (int off = 1; off < 1024; off <<= 1){
    int t = (tid >= off) ? buf[tid - off] : 0;
    __syncthreads();
    acc += t; buf[tid] = acc;
    __syncthreads();
  }
  if (i < n) offs[i] = acc - v;
  if (tid == 1023) bsums[blockIdx.x] = acc;
}

__global__ void scanB_k(int* __restrict__ bsums, int nb){
  if (threadIdx.x == 0 && blockIdx.x == 0){
    int run = 0;
    for (int i = 0; i < nb; i++){ int t = bsums[i]; bsums[i] = run; run += t; }
  }
}

__global__ __launch_bounds__(256)
void scanC_k(int* __restrict__ offs, const int* __restrict__ bsums,
             int* __restrict__ cursor, int n, int total){
  int i = blockIdx.x * 256 + threadIdx.x;
  if (i < n){
    int v = offs[i] + bsums[i >> 10];
    offs[i] = v;
    cursor[i] = v;
  }
  if (i == 0) offs[n] = total;
}

__global__ __launch_bounds__(256)
void sort_k(const int* __restrict__ ei, int E0, int Etot,
            int* __restrict__ cursor, int* __restrict__ srcs){
  int e = blockIdx.x * 256 + threadIdx.x;
  if (e >= Etot) return;
  int s, d;
  if (e < E0){ s = ei[e]; d = ei[E0 + e]; } else { s = d = e - E0; }
  int pos = atomicAdd(&cursor[d], 1);
  srcs[pos] = s;
}

// online-softmax lane combine: (mx, sm) pairs across 64 lanes
__device__ __forceinline__ void combine64(float& mx, float& sm){
  #pragma unroll
  for (int o = 32; o > 0; o >>= 1){
    float mo = __shfl_xor(mx, o);
    float so = __shfl_xor(sm, o);
    float mn = fmaxf(mx, mo);
    sm = sm * __expf(mx - mn) + so * __expf(mo - mn);
    mx = mn;
  }
}

// ---------------- fused GAT aggregation, layer 1 (H=4, D=64) ----------------
// block = 256 = 4 waves; wave = head; pass1 online softmax, pass2 weighted gather
__global__ __launch_bounds__(256)
void gat_aggr1_k(const int* __restrict__ offs, const int* __restrict__ srcs,
                 const bf16* __restrict__ h, const float* __restrict__ as,
                 const float* __restrict__ ad, const float* __restrict__ b,
                 float* __restrict__ out, int n){
  int node = blockIdx.x;
  if (node >= n) return;
  int hh   = threadIdx.x >> 6;
  int lane = threadIdx.x & 63;
  int beg = offs[node], end = offs[node + 1];
  float adv = ad[node * 4 + hh];
  // pass 1: online max+sum
  float mx = -1e30f, sm = 0.f;
  for (int j = beg + lane; j < end; j += 64){
    float e = as[srcs[j] * 4 + hh] + adv;
    e = e > 0.f ? e : 0.2f * e;
    float nm = fmaxf(mx, e);
    sm = sm * __expf(mx - nm) + __expf(e - nm);
    mx = nm;
  }
  combine64(mx, sm);
  float inv = 1.f / (sm + 1e-16f);
  // pass 2: weighted gather (lane = feature)
  float acc = 0.f;
  int j = beg;
  for (; j + 1 < end; j += 2){
    int s0 = srcs[j], s1 = srcs[j + 1];
    float e0 = as[s0 * 4 + hh] + adv; e0 = e0 > 0.f ? e0 : 0.2f * e0;
    float e1 = as[s1 * 4 + hh] + adv; e1 = e1 > 0.f ? e1 : 0.2f * e1;
    float a0 = __expf(e0 - mx) * inv;
    float a1 = __expf(e1 - mx) * inv;
    float h0 = __bfloat162float(h[(size_t)s0 * 256 + hh * 64 + lane]);
    float h1v = __bfloat162float(h[(size_t)s1 * 256 + hh * 64 + lane]);
    acc = fmaf(h0, a0, acc);
    acc = fmaf(h1v, a1, acc);
  }
  if (j < end){
    int s0 = srcs[j];
    float e0 = as[s0 * 4 + hh] + adv; e0 = e0 > 0.f ? e0 : 0.2f * e0;
    acc = fmaf(__bfloat162float(h[(size_t)s0 * 256 + hh * 64 + lane]),
               __expf(e0 - mx) * inv, acc);
  }
  float v = acc + b[hh * 64 + lane];
  out[(size_t)node * 256 + hh * 64 + lane] = v > 0.f ? v : 0.f;  // bias + ReLU
}

// ---------------- fused GAT aggregation, mu & logstd (H=1, D=64) ----------------
__global__ __launch_bounds__(128)
void gat_aggr2_k(const int* __restrict__ offs, const int* __restrict__ srcs,
                 const bf16* __restrict__ hmu, const bf16* __restrict__ hls,
                 const float* __restrict__ asMu, const float* __restrict__ adMu,
                 const float* __restrict__ asLs, const float* __restrict__ adLs,
                 const float* __restrict__ bmu, const float* __restrict__ bls,
                 float* __restrict__ outmu, float* __restrict__ outls, int n){
  int node = blockIdx.x;
  if (node >= n) return;
  int wave = threadIdx.x >> 6;
  int lane = threadIdx.x & 63;
  const float* as  = wave ? asLs : asMu;
  const float* adp = wave ? adLs : adMu;
  const bf16*  h   = wave ? hls : hmu;
  const float* bb  = wave ? bls : bmu;
  float* out = wave ? outls : outmu;
  int beg = offs[node], end = offs[node + 1];
  float adv = adp[node];
  float mx = -1e30f, sm = 0.f;
  for (int j = beg + lane; j < end; j += 64){
    float e = as[srcs[j]] + adv;
    e = e > 0.f ? e : 0.2f * e;
    float nm = fmaxf(mx, e);
    sm = sm * __expf(mx - nm) + __expf(e - nm);
    mx = nm;
  }
  combine64(mx, sm);
  float inv = 1.f / (sm + 1e-16f);
  float acc = 0.f;
  int j = beg;
  for (; j + 1 < end; j += 2){
    int s0 = srcs[j], s1 = srcs[j + 1];
    float e0 = as[s0] + adv; e0 = e0 > 0.f ? e0 : 0.2f * e0;
    float e1 = as[s1] + adv; e1 = e1 > 0.f ? e1 : 0.2f * e1;
    float a0 = __expf(e0 - mx) * inv;
    float a1 = __expf(e1 - mx) * inv;
    acc = fmaf(__bfloat162float(h[(size_t)s0 * 64 + lane]), a0, acc);
    acc = fmaf(__bfloat162float(h[(size_t)s1 * 64 + lane]), a1, acc);
  }
  if (j < end){
    int s0 = srcs[j];
    float e0 = as[s0] + adv; e0 = e0 > 0.f ? e0 : 0.2f * e0;
    acc = fmaf(__bfloat162float(h[(size_t)s0 * 64 + lane]), __expf(e0 - mx) * inv, acc);
  }
  out[(size_t)node * 64 + lane] = acc + bb[lane];
}

extern "C" void kernel_launch(void* const* d_in, const int* in_sizes, int n_in,
                              void* d_out, int out_size, void* d_ws, size_t ws_size,
                              hipStream_t stream){
  const float* x    = (const float*)d_in[0];
  const int*   ei   = (const int*)d_in[1];
  const float* W1   = (const float*)d_in[2];
  const float* aS1  = (const float*)d_in[3];
  const float* aD1  = (const float*)d_in[4];
  const float* b1   = (const float*)d_in[5];
  const float* Wmu  = (const float*)d_in[6];
  const float* aSmu = (const float*)d_in[7];
  const float* aDmu = (const float*)d_in[8];
  const float* bmu  = (const float*)d_in[9];
  const float* Wls  = (const float*)d_in[10];
  const float* aSls = (const float*)d_in[11];
  const float* aDls = (const float*)d_in[12];
  const float* bls  = (const float*)d_in[13];

  const int N    = NNODES;
  const int E0   = in_sizes[1] / 2;
  const int Etot = E0 + N;

  // ---- workspace layout (float units) ----
  float* ws   = (float*)d_ws;
  float* bbuf = ws;                          // [0, 12.8M) f32: layer-1 output
  bf16*  h1bf = (bf16*)(ws + 12800000);      // 12.8M bf16 -> [12.8M, 19.2M)
  bf16*  h2mu = (bf16*)(ws + 19200000);      // 3.2M bf16 -> [19.2M, 20.8M)
  bf16*  h2ls = (bf16*)(ws + 20800000);      // 3.2M bf16 -> [20.8M, 22.4M)
  float* as1  = ws + 22400000;               // 200K
  float* ad1  = ws + 22600000;               // 200K
  int* cnt    = (int*)(ws + 22800000);       // 50K (dead before as1 written? no - separate)
  int* cursor = cnt + 50000;                 // 50K
  float* as2m = as1;                         // overlays, as1 dead after aggr1
  float* ad2m = as1 + 50000;
  float* as2l = as1 + 100000;
  float* ad2l = as1 + 150000;
  int* offs  = (int*)(ws + 23000000);        // 50001
  int* srcs  = offs + 50001;                 // 850000
  int* bsums = srcs + 850000;                // 64

  float* outmu = (float*)d_out;
  float* outls = (float*)d_out + 3200000;

  const int egrid = (Etot + 255) / 256;

  // ---- CSR build (shared by all 3 convs) ----
  hipMemsetAsync(cnt, 0, 50000 * sizeof(int), stream);
  hist_k<<<egrid, 256, 0, stream>>>(ei, E0, Etot, cnt);
  scanA_k<<<(N + 1023) / 1024, 1024, 0, stream>>>(cnt, offs, bsums, N);
  scanB_k<<<1, 64, 0, stream>>>(bsums, (N + 1023) / 1024);
  scanC_k<<<(N + 256) / 256, 256, 0, stream>>>(offs, bsums, cursor, N, Etot);
  sort_k<<<egrid, 256, 0, stream>>>(ei, E0, Etot, cursor, srcs);

  // ---- layer 1: GATConv(128 -> 4x64, concat) + bias + ReLU ----
  gemm_k<128, 256, 32><<<(N + 31) / 32, 256, 0, stream>>>(x, W1, h1bf, N);
  alpha_k<4><<<(N * 4 + 255) / 256, 256, 0, stream>>>(h1bf, aS1, aD1, as1, ad1, N);
  gat_aggr1_k<<<N, 256, 0, stream>>>(offs, srcs, h1bf, as1, ad1, b1, bbuf, N);

  // ---- layers mu & logstd: GATConv(256 -> 1x64) + bias ----
  gemm_k<256, 64, 32><<<(N + 31) / 32, 256, 0, stream>>>(bbuf, Wmu, h2mu, N);
  gemm_k<256, 64, 32><<<(N + 31) / 32, 256, 0, stream>>>(bbuf, Wls, h2ls, N);
  alpha_k<1><<<(N + 255) / 256, 256, 0, stream>>>(h2mu, aSmu, aDmu, as2m, ad2m, N);
  alpha_k<1><<<(N + 255) / 256, 256, 0, stream>>>(h2ls, aSls, aDls, as2l, ad2l, N);
  gat_aggr2_k<<<N, 128, 0, stream>>>(offs, srcs, h2mu, h2ls,
                                     as2m, ad2m, as2l, ad2l,
                                     bmu, bls, outmu, outls, N);
}

// Round 4
// 512.090 us; speedup vs baseline: 3.5052x; 1.0158x over previous
//
#include <hip/hip_runtime.h>
#include <hip/hip_bf16.h>

#define NNODES 50000
typedef __hip_bfloat16 bf16;

// ---------------- GEMM: Ybf[nrows,NCOL] = bf16( X[nrows,K] @ W[K,NCOL] ) ----------------
template<int K, int NCOL, int ROWS>
__global__ __launch_bounds__(256)
void gemm_k(const float* __restrict__ X, const float* __restrict__ W,
            bf16* __restrict__ Ybf, int nrows){
  constexpr int G = 256 / NCOL;
  constexpr int RPT = ROWS / G;
  __shared__ float xs[ROWS][K + 4];
  const int row0 = blockIdx.x * ROWS;
  const int tid = threadIdx.x;
  for (int i = tid * 4; i < ROWS * K; i += 1024){
    int r = i / K, k = i - r * K;
    int gr = row0 + r;
    float4 v = make_float4(0.f, 0.f, 0.f, 0.f);
    if (gr < nrows) v = *(const float4*)(X + (size_t)gr * K + k);
    *(float4*)&xs[r][k] = v;
  }
  __syncthreads();
  const int j = tid % NCOL;
  const int g = tid / NCOL;
  float acc[RPT];
  #pragma unroll
  for (int r = 0; r < RPT; r++) acc[r] = 0.f;
  for (int k = 0; k < K; k += 4){
    float w0 = W[(k + 0) * NCOL + j];
    float w1 = W[(k + 1) * NCOL + j];
    float w2 = W[(k + 2) * NCOL + j];
    float w3 = W[(k + 3) * NCOL + j];
    #pragma unroll
    for (int r = 0; r < RPT; r++){
      float4 xv = *(const float4*)&xs[g + r * G][k];
      acc[r] = fmaf(xv.x, w0, acc[r]);
      acc[r] = fmaf(xv.y, w1, acc[r]);
      acc[r] = fmaf(xv.z, w2, acc[r]);
      acc[r] = fmaf(xv.w, w3, acc[r]);
    }
  }
  #pragma unroll
  for (int r = 0; r < RPT; r++){
    int gr = row0 + g + r * G;
    if (gr < nrows) Ybf[(size_t)gr * NCOL + j] = __float2bfloat16(acc[r]);
  }
}

// dual 64-col GEMM: reads X once, writes bf16 Ya and Yb (mu & logstd heads)
template<int K, int ROWS>
__global__ __launch_bounds__(256)
void gemm_dual_k(const float* __restrict__ X, const float* __restrict__ Wa,
                 const float* __restrict__ Wb, bf16* __restrict__ Ya,
                 bf16* __restrict__ Yb, int nrows){
  constexpr int RPT = ROWS / 2;
  __shared__ float xs[ROWS][K + 4];
  const int row0 = blockIdx.x * ROWS;
  const int tid = threadIdx.x;
  for (int i = tid * 4; i < ROWS * K; i += 1024){
    int r = i / K, k = i - r * K;
    int gr = row0 + r;
    float4 v = make_float4(0.f, 0.f, 0.f, 0.f);
    if (gr < nrows) v = *(const float4*)(X + (size_t)gr * K + k);
    *(float4*)&xs[r][k] = v;
  }
  __syncthreads();
  const int j  = tid & 127;
  const int g  = tid >> 7;
  const int jj = j & 63;
  const float* W = (j < 64) ? Wa : Wb;
  bf16* Y = (j < 64) ? Ya : Yb;
  float acc[RPT];
  #pragma unroll
  for (int r = 0; r < RPT; r++) acc[r] = 0.f;
  for (int k = 0; k < K; k += 4){
    float w0 = W[(k + 0) * 64 + jj];
    float w1 = W[(k + 1) * 64 + jj];
    float w2 = W[(k + 2) * 64 + jj];
    float w3 = W[(k + 3) * 64 + jj];
    #pragma unroll
    for (int r = 0; r < RPT; r++){
      float4 xv = *(const float4*)&xs[g + r * 2][k];
      acc[r] = fmaf(xv.x, w0, acc[r]);
      acc[r] = fmaf(xv.y, w1, acc[r]);
      acc[r] = fmaf(xv.z, w2, acc[r]);
      acc[r] = fmaf(xv.w, w3, acc[r]);
    }
  }
  #pragma unroll
  for (int r = 0; r < RPT; r++){
    int gr = row0 + g + r * 2;
    if (gr < nrows) Y[(size_t)gr * 64 + jj] = __float2bfloat16(acc[r]);
  }
}

// ---------------- per-node attention logits from bf16 h ----------------
template<int H>
__global__ __launch_bounds__(256)
void alpha_k(const bf16* __restrict__ h, const float* __restrict__ a_s,
             const float* __restrict__ a_d, float* __restrict__ os,
             float* __restrict__ od, int n){
  int i = blockIdx.x * 256 + threadIdx.x;
  if (i >= n * H) return;
  int hh = i % H;
  const uint4* hp  = (const uint4*)(h + (size_t)i * 64);
  const float* asp = a_s + hh * 64;
  const float* adp = a_d + hh * 64;
  float s1 = 0.f, s2 = 0.f;
  #pragma unroll
  for (int q = 0; q < 8; q++){
    uint4 v = hp[q];
    unsigned w[4] = {v.x, v.y, v.z, v.w};
    #pragma unroll
    for (int p = 0; p < 4; p++){
      float lo = __uint_as_float(w[p] << 16);
      float hi = __uint_as_float(w[p] & 0xffff0000u);
      int d = q * 8 + p * 2;
      s1 = fmaf(lo, asp[d], s1);     s2 = fmaf(lo, adp[d], s2);
      s1 = fmaf(hi, asp[d + 1], s1); s2 = fmaf(hi, adp[d + 1], s2);
    }
  }
  os[i] = s1; od[i] = s2;
}

// ---------------- CSR build ----------------
__global__ __launch_bounds__(256)
void hist_k(const int* __restrict__ ei, int E0, int Etot, int* __restrict__ cnt){
  int e = blockIdx.x * 256 + threadIdx.x;
  if (e >= Etot) return;
  int d = (e < E0) ? ei[E0 + e] : e - E0;
  atomicAdd(&cnt[d], 1);
}

__global__ __launch_bounds__(1024)
void scanA_k(const int* __restrict__ cnt, int* __restrict__ offs,
             int* __restrict__ bsums, int n){
  __shared__ int buf[1024];
  int tid = threadIdx.x;
  int i = blockIdx.x * 1024 + tid;
  int v = (i < n) ? cnt[i] : 0;
  buf[tid] = v; __syncthreads();
  int acc = v;
  for (int off = 1; off < 1024; off <<= 1){
    int t = (tid >= off) ? buf[tid - off] : 0;
    __syncthreads();
    acc += t; buf[tid] = acc;
    __syncthreads();
  }
  if (i < n) offs[i] = acc - v;
  if (tid == 1023) bsums[blockIdx.x] = acc;
}

__global__ void scanB_k(int* __restrict__ bsums, int nb){
  if (threadIdx.x == 0 && blockIdx.x == 0){
    int run = 0;
    for (int i = 0; i < nb; i++){ int t = bsums[i]; bsums[i] = run; run += t; }
  }
}

__global__ __launch_bounds__(256)
void scanC_k(int* __restrict__ offs, const int* __restrict__ bsums,
             int* __restrict__ cursor, int n, int total){
  int i = blockIdx.x * 256 + threadIdx.x;
  if (i < n){
    int v = offs[i] + bsums[i >> 10];
    offs[i] = v;
    cursor[i] = v;
  }
  if (i == 0) offs[n] = total;
}

__global__ __launch_bounds__(256)
void sort_k(const int* __restrict__ ei, int E0, int Etot,
            int* __restrict__ cursor, int* __restrict__ srcs,
            int* __restrict__ dsts){
  int e = blockIdx.x * 256 + threadIdx.x;
  if (e >= Etot) return;
  int s, d;
  if (e < E0){ s = ei[e]; d = ei[E0 + e]; } else { s = d = e - E0; }
  int pos = atomicAdd(&cursor[d], 1);
  srcs[pos] = s;
  dsts[pos] = d;
}

// ---------------- edge-parallel logits (leaky applied), SoA by head ----------------
__global__ __launch_bounds__(256)
void logit1_k(const int* __restrict__ srcs, const int* __restrict__ dsts,
              const float* __restrict__ as, const float* __restrict__ ad,
              float* __restrict__ e1, int Etot){
  int j = blockIdx.x * 256 + threadIdx.x;
  if (j >= Etot) return;
  int s = srcs[j], d = dsts[j];
  float4 av = *(const float4*)(as + s * 4);
  float4 dv = *(const float4*)(ad + d * 4);
  float e0 = av.x + dv.x; e0 = e0 > 0.f ? e0 : 0.2f * e0;
  float e1v = av.y + dv.y; e1v = e1v > 0.f ? e1v : 0.2f * e1v;
  float e2 = av.z + dv.z; e2 = e2 > 0.f ? e2 : 0.2f * e2;
  float e3 = av.w + dv.w; e3 = e3 > 0.f ? e3 : 0.2f * e3;
  e1[j] = e0; e1[Etot + j] = e1v; e1[2 * Etot + j] = e2; e1[3 * Etot + j] = e3;
}

__global__ __launch_bounds__(256)
void logit2_k(const int* __restrict__ srcs, const int* __restrict__ dsts,
              const float* __restrict__ asm_, const float* __restrict__ adm,
              const float* __restrict__ asl, const float* __restrict__ adl,
              float* __restrict__ em, float* __restrict__ el, int Etot){
  int j = blockIdx.x * 256 + threadIdx.x;
  if (j >= Etot) return;
  int s = srcs[j], d = dsts[j];
  float a = asm_[s] + adm[d]; a = a > 0.f ? a : 0.2f * a;
  float b = asl[s] + adl[d]; b = b > 0.f ? b : 0.2f * b;
  em[j] = a; el[j] = b;
}

// ---------------- fused aggregation, layer 1 (H=4, D=64) ----------------
// block = 256 = 4 waves; wave = head. Paired-lane pass2: lanes 0-31 even edge,
// lanes 32-63 odd edge, each lane owns a dword feature-pair.
__global__ __launch_bounds__(256)
void gat_aggr1_k(const int* __restrict__ offs, const int* __restrict__ srcs,
                 const float* __restrict__ e1, const bf16* __restrict__ h,
                 const float* __restrict__ b, float* __restrict__ out,
                 int n, int Etot){
  int node = blockIdx.x;
  if (node >= n) return;
  int hh   = threadIdx.x >> 6;
  int lane = threadIdx.x & 63;
  int beg = offs[node], end = offs[node + 1];
  const float* eH = e1 + (size_t)hh * Etot;
  // pass A: max
  float mx = -1e30f;
  for (int j = beg + lane; j < end; j += 64) mx = fmaxf(mx, eH[j]);
  #pragma unroll
  for (int o = 32; o > 0; o >>= 1) mx = fmaxf(mx, __shfl_xor(mx, o));
  // pass B: sum
  float sm = 0.f;
  for (int j = beg + lane; j < end; j += 64) sm += __expf(eH[j] - mx);
  #pragma unroll
  for (int o = 32; o > 0; o >>= 1) sm += __shfl_xor(sm, o);
  float inv = 1.f / (sm + 1e-16f);
  // pass 2: paired-lane weighted gather
  int half  = lane >> 5;
  int fpair = lane & 31;
  float acc0 = 0.f, acc1 = 0.f;
  for (int j0 = beg; j0 < end; j0 += 64){
    int nj = end - j0; if (nj > 64) nj = 64;
    float aL = 0.f; int sL = 0;
    if (lane < nj){
      sL = srcs[j0 + lane];
      aL = __expf(eH[j0 + lane] - mx) * inv;
    }
    for (int t = 0; t < nj; t += 2){
      int idx = t + half;                    // <= 63 always
      float a = __shfl(aL, idx);             // 0 for idx >= nj
      int s   = __shfl(sL, idx);
      unsigned dw = *(const unsigned*)(h + (size_t)s * 256 + hh * 64 + fpair * 2);
      float lo = __uint_as_float(dw << 16);
      float hi = __uint_as_float(dw & 0xffff0000u);
      acc0 = fmaf(lo, a, acc0);
      acc1 = fmaf(hi, a, acc1);
    }
  }
  acc0 += __shfl_xor(acc0, 32);
  acc1 += __shfl_xor(acc1, 32);
  if (lane < 32){
    float v0 = acc0 + b[hh * 64 + fpair * 2];
    float v1 = acc1 + b[hh * 64 + fpair * 2 + 1];
    float2 v = make_float2(v0 > 0.f ? v0 : 0.f, v1 > 0.f ? v1 : 0.f);
    *(float2*)(out + (size_t)node * 256 + hh * 64 + fpair * 2) = v;
  }
}

// ---------------- fused aggregation, mu & logstd (H=1, D=64) ----------------
// block = 128 = 2 waves; wave 0 -> mu, wave 1 -> logstd
__global__ __launch_bounds__(128)
void gat_aggr2_k(const int* __restrict__ offs, const int* __restrict__ srcs,
                 const float* __restrict__ em, const float* __restrict__ el,
                 const bf16* __restrict__ hmu, const bf16* __restrict__ hls,
                 const float* __restrict__ bmu, const float* __restrict__ bls,
                 float* __restrict__ outmu, float* __restrict__ outls, int n){
  int node = blockIdx.x;
  if (node >= n) return;
  int wave = threadIdx.x >> 6;
  int lane = threadIdx.x & 63;
  const float* eH = wave ? el : em;
  const bf16*  h  = wave ? hls : hmu;
  const float* bb = wave ? bls : bmu;
  float* out = wave ? outls : outmu;
  int beg = offs[node], end = offs[node + 1];
  float mx = -1e30f;
  for (int j = beg + lane; j < end; j += 64) mx = fmaxf(mx, eH[j]);
  #pragma unroll
  for (int o = 32; o > 0; o >>= 1) mx = fmaxf(mx, __shfl_xor(mx, o));
  float sm = 0.f;
  for (int j = beg + lane; j < end; j += 64) sm += __expf(eH[j] - mx);
  #pragma unroll
  for (int o = 32; o > 0; o >>= 1) sm += __shfl_xor(sm, o);
  float inv = 1.f / (sm + 1e-16f);
  int half  = lane >> 5;
  int fpair = lane & 31;
  float acc0 = 0.f, acc1 = 0.f;
  for (int j0 = beg; j0 < end; j0 += 64){
    int nj = end - j0; if (nj > 64) nj = 64;
    float aL = 0.f; int sL = 0;
    if (lane < nj){
      sL = srcs[j0 + lane];
      aL = __expf(eH[j0 + lane] - mx) * inv;
    }
    for (int t = 0; t < nj; t += 2){
      int idx = t + half;
      float a = __shfl(aL, idx);
      int s   = __shfl(sL, idx);
      unsigned dw = *(const unsigned*)(h + (size_t)s * 64 + fpair * 2);
      float lo = __uint_as_float(dw << 16);
      float hi = __uint_as_float(dw & 0xffff0000u);
      acc0 = fmaf(lo, a, acc0);
      acc1 = fmaf(hi, a, acc1);
    }
  }
  acc0 += __shfl_xor(acc0, 32);
  acc1 += __shfl_xor(acc1, 32);
  if (lane < 32){
    float2 v = make_float2(acc0 + bb[fpair * 2], acc1 + bb[fpair * 2 + 1]);
    *(float2*)(out + (size_t)node * 64 + fpair * 2) = v;
  }
}

extern "C" void kernel_launch(void* const* d_in, const int* in_sizes, int n_in,
                              void* d_out, int out_size, void* d_ws, size_t ws_size,
                              hipStream_t stream){
  const float* x    = (const float*)d_in[0];
  const int*   ei   = (const int*)d_in[1];
  const float* W1   = (const float*)d_in[2];
  const float* aS1  = (const float*)d_in[3];
  const float* aD1  = (const float*)d_in[4];
  const float* b1   = (const float*)d_in[5];
  const float* Wmu  = (const float*)d_in[6];
  const float* aSmu = (const float*)d_in[7];
  const float* aDmu = (const float*)d_in[8];
  const float* bmu  = (const float*)d_in[9];
  const float* Wls  = (const float*)d_in[10];
  const float* aSls = (const float*)d_in[11];
  const float* aDls = (const float*)d_in[12];
  const float* bls  = (const float*)d_in[13];

  const int N    = NNODES;
  const int E0   = in_sizes[1] / 2;
  const int Etot = E0 + N;

  // ---- workspace layout (float units) ----
  float* ws   = (float*)d_ws;
  float* bbuf = ws;                          // [0, 12.8M) f32 layer-1 out
  bf16*  h1bf = (bf16*)(ws + 12800000);      // [12.8M, 19.2M) 12.8M bf16
  float* e1   = ws + 19200000;               // [19.2M, 22.6M) 4*Etot f32  (dead after aggr1)
  bf16*  h2mu = (bf16*)(ws + 19200000);      // overlay on e1 after aggr1: 3.2M bf16
  bf16*  h2ls = (bf16*)(ws + 20800000);      //                           3.2M bf16
  float* e2m  = ws + 22600000;               // Etot f32
  float* e2l  = ws + 23450000;               // Etot f32
  float* as1  = ws + 24300000;               // 200K
  float* ad1  = ws + 24500000;               // 200K
  float* as2m = as1;                         // overlays, as1/ad1 dead after logit1
  float* ad2m = as1 + 50000;
  float* as2l = as1 + 100000;
  float* ad2l = as1 + 150000;
  int* cnt    = (int*)(ws + 24700000);       // 50K
  int* cursor = cnt + 50000;                 // 50K
  int* offs   = (int*)(ws + 24800000);       // 50001
  int* srcs   = offs + 50001;                // 850000
  int* dsts   = srcs + 850000;               // 850000
  int* bsums  = dsts + 850000;               // 64

  float* outmu = (float*)d_out;
  float* outls = (float*)d_out + 3200000;

  const int egrid = (Etot + 255) / 256;

  // ---- CSR build (shared by all 3 convs) ----
  hipMemsetAsync(cnt, 0, 50000 * sizeof(int), stream);
  hist_k<<<egrid, 256, 0, stream>>>(ei, E0, Etot, cnt);
  scanA_k<<<(N + 1023) / 1024, 1024, 0, stream>>>(cnt, offs, bsums, N);
  scanB_k<<<1, 64, 0, stream>>>(bsums, (N + 1023) / 1024);
  scanC_k<<<(N + 256) / 256, 256, 0, stream>>>(offs, bsums, cursor, N, Etot);
  sort_k<<<egrid, 256, 0, stream>>>(ei, E0, Etot, cursor, srcs, dsts);

  // ---- layer 1: GATConv(128 -> 4x64, concat) + bias + ReLU ----
  gemm_k<128, 256, 32><<<(N + 31) / 32, 256, 0, stream>>>(x, W1, h1bf, N);
  alpha_k<4><<<(N * 4 + 255) / 256, 256, 0, stream>>>(h1bf, aS1, aD1, as1, ad1, N);
  logit1_k<<<egrid, 256, 0, stream>>>(srcs, dsts, as1, ad1, e1, Etot);
  gat_aggr1_k<<<N, 256, 0, stream>>>(offs, srcs, e1, h1bf, b1, bbuf, N, Etot);

  // ---- layers mu & logstd: GATConv(256 -> 1x64) + bias ----
  gemm_dual_k<256, 32><<<(N + 31) / 32, 256, 0, stream>>>(bbuf, Wmu, Wls, h2mu, h2ls, N);
  alpha_k<1><<<(N + 255) / 256, 256, 0, stream>>>(h2mu, aSmu, aDmu, as2m, ad2m, N);
  alpha_k<1><<<(N + 255) / 256, 256, 0, stream>>>(h2ls, aSls, aDls, as2l, ad2l, N);
  logit2_k<<<egrid, 256, 0, stream>>>(srcs, dsts, as2m, ad2m, as2l, ad2l, e2m, e2l, Etot);
  gat_aggr2_k<<<N, 128, 0, stream>>>(offs, srcs, e2m, e2l, h2mu, h2ls,
                                     bmu, bls, outmu, outls, N);
}

// Round 5
// 464.419 us; speedup vs baseline: 3.8650x; 1.1026x over previous
//
#include <hip/hip_runtime.h>
#include <hip/hip_bf16.h>

#define NNODES 50000
typedef __hip_bfloat16 bf16;

__device__ __forceinline__ void unpack2(unsigned w, float& lo, float& hi){
  lo = __uint_as_float(w << 16);
  hi = __uint_as_float(w & 0xffff0000u);
}

// ---------------- GEMM: Ybf[nrows,NCOL] = bf16( X[nrows,K] @ W[K,NCOL] ) ----------------
template<int K, int NCOL, int ROWS>
__global__ __launch_bounds__(256)
void gemm_k(const float* __restrict__ X, const float* __restrict__ W,
            bf16* __restrict__ Ybf, int nrows){
  constexpr int G = 256 / NCOL;
  constexpr int RPT = ROWS / G;
  __shared__ float xs[ROWS][K + 4];
  const int row0 = blockIdx.x * ROWS;
  const int tid = threadIdx.x;
  for (int i = tid * 4; i < ROWS * K; i += 1024){
    int r = i / K, k = i - r * K;
    int gr = row0 + r;
    float4 v = make_float4(0.f, 0.f, 0.f, 0.f);
    if (gr < nrows) v = *(const float4*)(X + (size_t)gr * K + k);
    *(float4*)&xs[r][k] = v;
  }
  __syncthreads();
  const int j = tid % NCOL;
  const int g = tid / NCOL;
  float acc[RPT];
  #pragma unroll
  for (int r = 0; r < RPT; r++) acc[r] = 0.f;
  for (int k = 0; k < K; k += 4){
    float w0 = W[(k + 0) * NCOL + j];
    float w1 = W[(k + 1) * NCOL + j];
    float w2 = W[(k + 2) * NCOL + j];
    float w3 = W[(k + 3) * NCOL + j];
    #pragma unroll
    for (int r = 0; r < RPT; r++){
      float4 xv = *(const float4*)&xs[g + r * G][k];
      acc[r] = fmaf(xv.x, w0, acc[r]);
      acc[r] = fmaf(xv.y, w1, acc[r]);
      acc[r] = fmaf(xv.z, w2, acc[r]);
      acc[r] = fmaf(xv.w, w3, acc[r]);
    }
  }
  #pragma unroll
  for (int r = 0; r < RPT; r++){
    int gr = row0 + g + r * G;
    if (gr < nrows) Ybf[(size_t)gr * NCOL + j] = __float2bfloat16(acc[r]);
  }
}

// dual 64-col GEMM: reads X once, writes bf16 Ya and Yb (mu & logstd heads)
template<int K, int ROWS>
__global__ __launch_bounds__(256)
void gemm_dual_k(const float* __restrict__ X, const float* __restrict__ Wa,
                 const float* __restrict__ Wb, bf16* __restrict__ Ya,
                 bf16* __restrict__ Yb, int nrows){
  constexpr int RPT = ROWS / 2;
  __shared__ float xs[ROWS][K + 4];
  const int row0 = blockIdx.x * ROWS;
  const int tid = threadIdx.x;
  for (int i = tid * 4; i < ROWS * K; i += 1024){
    int r = i / K, k = i - r * K;
    int gr = row0 + r;
    float4 v = make_float4(0.f, 0.f, 0.f, 0.f);
    if (gr < nrows) v = *(const float4*)(X + (size_t)gr * K + k);
    *(float4*)&xs[r][k] = v;
  }
  __syncthreads();
  const int j  = tid & 127;
  const int g  = tid >> 7;
  const int jj = j & 63;
  const float* W = (j < 64) ? Wa : Wb;
  bf16* Y = (j < 64) ? Ya : Yb;
  float acc[RPT];
  #pragma unroll
  for (int r = 0; r < RPT; r++) acc[r] = 0.f;
  for (int k = 0; k < K; k += 4){
    float w0 = W[(k + 0) * 64 + jj];
    float w1 = W[(k + 1) * 64 + jj];
    float w2 = W[(k + 2) * 64 + jj];
    float w3 = W[(k + 3) * 64 + jj];
    #pragma unroll
    for (int r = 0; r < RPT; r++){
      float4 xv = *(const float4*)&xs[g + r * 2][k];
      acc[r] = fmaf(xv.x, w0, acc[r]);
      acc[r] = fmaf(xv.y, w1, acc[r]);
      acc[r] = fmaf(xv.z, w2, acc[r]);
      acc[r] = fmaf(xv.w, w3, acc[r]);
    }
  }
  #pragma unroll
  for (int r = 0; r < RPT; r++){
    int gr = row0 + g + r * 2;
    if (gr < nrows) Y[(size_t)gr * 64 + jj] = __float2bfloat16(acc[r]);
  }
}

// ---------------- per-node attention logits from bf16 h ----------------
template<int H>
__global__ __launch_bounds__(256)
void alpha_k(const bf16* __restrict__ h, const float* __restrict__ a_s,
             const float* __restrict__ a_d, float* __restrict__ os,
             float* __restrict__ od, int n){
  int i = blockIdx.x * 256 + threadIdx.x;
  if (i >= n * H) return;
  int hh = i % H;
  const uint4* hp  = (const uint4*)(h + (size_t)i * 64);
  const float* asp = a_s + hh * 64;
  const float* adp = a_d + hh * 64;
  float s1 = 0.f, s2 = 0.f;
  #pragma unroll
  for (int q = 0; q < 8; q++){
    uint4 v = hp[q];
    unsigned w[4] = {v.x, v.y, v.z, v.w};
    #pragma unroll
    for (int p = 0; p < 4; p++){
      float lo, hi; unpack2(w[p], lo, hi);
      int d = q * 8 + p * 2;
      s1 = fmaf(lo, asp[d], s1);     s2 = fmaf(lo, adp[d], s2);
      s1 = fmaf(hi, asp[d + 1], s1); s2 = fmaf(hi, adp[d + 1], s2);
    }
  }
  os[i] = s1; od[i] = s2;
}

// ---------------- CSR build ----------------
__global__ __launch_bounds__(256)
void hist_k(const int* __restrict__ ei, int E0, int Etot, int* __restrict__ cnt){
  int e = blockIdx.x * 256 + threadIdx.x;
  if (e >= Etot) return;
  int d = (e < E0) ? ei[E0 + e] : e - E0;
  atomicAdd(&cnt[d], 1);
}

__global__ __launch_bounds__(1024)
void scanA_k(const int* __restrict__ cnt, int* __restrict__ offs,
             int* __restrict__ bsums, int n){
  __shared__ int buf[1024];
  int tid = threadIdx.x;
  int i = blockIdx.x * 1024 + tid;
  int v = (i < n) ? cnt[i] : 0;
  buf[tid] = v; __syncthreads();
  int acc = v;
  for (int off = 1; off < 1024; off <<= 1){
    int t = (tid >= off) ? buf[tid - off] : 0;
    __syncthreads();
    acc += t; buf[tid] = acc;
    __syncthreads();
  }
  if (i < n) offs[i] = acc - v;
  if (tid == 1023) bsums[blockIdx.x] = acc;
}

__global__ void scanB_k(int* __restrict__ bsums, int nb){
  if (threadIdx.x == 0 && blockIdx.x == 0){
    int run = 0;
    for (int i = 0; i < nb; i++){ int t = bsums[i]; bsums[i] = run; run += t; }
  }
}

__global__ __launch_bounds__(256)
void scanC_k(int* __restrict__ offs, const int* __restrict__ bsums,
             int* __restrict__ cursor, int n, int total){
  int i = blockIdx.x * 256 + threadIdx.x;
  if (i < n){
    int v = offs[i] + bsums[i >> 10];
    offs[i] = v;
    cursor[i] = v;
  }
  if (i == 0) offs[n] = total;
}

__global__ __launch_bounds__(256)
void sort_k(const int* __restrict__ ei, int E0, int Etot,
            int* __restrict__ cursor, int* __restrict__ srcs,
            int* __restrict__ dsts){
  int e = blockIdx.x * 256 + threadIdx.x;
  if (e >= Etot) return;
  int s, d;
  if (e < E0){ s = ei[e]; d = ei[E0 + e]; } else { s = d = e - E0; }
  int pos = atomicAdd(&cursor[d], 1);
  srcs[pos] = s;
  dsts[pos] = d;
}

// ---------------- edge-parallel logits (leaky applied), SoA by head ----------------
__global__ __launch_bounds__(256)
void logit1_k(const int* __restrict__ srcs, const int* __restrict__ dsts,
              const float* __restrict__ as, const float* __restrict__ ad,
              float* __restrict__ e1, int Etot){
  int j = blockIdx.x * 256 + threadIdx.x;
  if (j >= Etot) return;
  int s = srcs[j], d = dsts[j];
  float4 av = *(const float4*)(as + s * 4);
  float4 dv = *(const float4*)(ad + d * 4);
  float e0 = av.x + dv.x; e0 = e0 > 0.f ? e0 : 0.2f * e0;
  float e1v = av.y + dv.y; e1v = e1v > 0.f ? e1v : 0.2f * e1v;
  float e2 = av.z + dv.z; e2 = e2 > 0.f ? e2 : 0.2f * e2;
  float e3 = av.w + dv.w; e3 = e3 > 0.f ? e3 : 0.2f * e3;
  e1[j] = e0; e1[Etot + j] = e1v; e1[2 * Etot + j] = e2; e1[3 * Etot + j] = e3;
}

__global__ __launch_bounds__(256)
void logit2_k(const int* __restrict__ srcs, const int* __restrict__ dsts,
              const float* __restrict__ asm_, const float* __restrict__ adm,
              const float* __restrict__ asl, const float* __restrict__ adl,
              float* __restrict__ em, float* __restrict__ el, int Etot){
  int j = blockIdx.x * 256 + threadIdx.x;
  if (j >= Etot) return;
  int s = srcs[j], d = dsts[j];
  float a = asm_[s] + adm[d]; a = a > 0.f ? a : 0.2f * a;
  float b = asl[s] + adl[d]; b = b > 0.f ? b : 0.2f * b;
  em[j] = a; el[j] = b;
}

// ---------------- fused aggregation, layer 1 (H=4, D=64) ----------------
// block = 256 = 4 waves; wave = head. Pass2: 8 lanes/edge (uint4 = 8 bf16 each),
// 8 edges in flight per wave for memory-level parallelism.
__global__ __launch_bounds__(256)
void gat_aggr1_k(const int* __restrict__ offs, const int* __restrict__ srcs,
                 const float* __restrict__ e1, const bf16* __restrict__ h,
                 const float* __restrict__ b, float* __restrict__ out,
                 int n, int Etot){
  int node = blockIdx.x;
  if (node >= n) return;
  int hh   = threadIdx.x >> 6;
  int lane = threadIdx.x & 63;
  int beg = offs[node], end = offs[node + 1];
  const float* eH = e1 + (size_t)hh * Etot;
  // pass A: max
  float mx = -1e30f;
  for (int j = beg + lane; j < end; j += 64) mx = fmaxf(mx, eH[j]);
  #pragma unroll
  for (int o = 32; o > 0; o >>= 1) mx = fmaxf(mx, __shfl_xor(mx, o));
  // pass B: sum
  float sm = 0.f;
  for (int j = beg + lane; j < end; j += 64) sm += __expf(eH[j] - mx);
  #pragma unroll
  for (int o = 32; o > 0; o >>= 1) sm += __shfl_xor(sm, o);
  float inv = 1.f / (sm + 1e-16f);
  // pass 2: 8 lanes per edge, 8 edges concurrent
  const int q = lane >> 3;   // edge slot
  const int f = lane & 7;    // feature octet
  float acc[8];
  #pragma unroll
  for (int i = 0; i < 8; i++) acc[i] = 0.f;
  for (int j0 = beg; j0 < end; j0 += 64){
    int nj = end - j0; if (nj > 64) nj = 64;
    float aL = 0.f; int sL = 0;
    if (lane < nj){
      sL = srcs[j0 + lane];
      aL = __expf(eH[j0 + lane] - mx) * inv;
    }
    for (int t = 0; t < nj; t += 8){
      int idx = t + q;                       // t%8==0, t<nj<=64 -> idx<=63
      float a = __shfl(aL, idx);             // 0 beyond nj
      int s   = __shfl(sL, idx);
      uint4 dw = *(const uint4*)(h + (size_t)s * 256 + hh * 64 + f * 8);
      float lo, hi;
      unpack2(dw.x, lo, hi); acc[0] = fmaf(lo, a, acc[0]); acc[1] = fmaf(hi, a, acc[1]);
      unpack2(dw.y, lo, hi); acc[2] = fmaf(lo, a, acc[2]); acc[3] = fmaf(hi, a, acc[3]);
      unpack2(dw.z, lo, hi); acc[4] = fmaf(lo, a, acc[4]); acc[5] = fmaf(hi, a, acc[5]);
      unpack2(dw.w, lo, hi); acc[6] = fmaf(lo, a, acc[6]); acc[7] = fmaf(hi, a, acc[7]);
    }
  }
  // fold the 8 edge slots
  #pragma unroll
  for (int o = 8; o < 64; o <<= 1){
    #pragma unroll
    for (int i = 0; i < 8; i++) acc[i] += __shfl_xor(acc[i], o);
  }
  if (lane < 8){
    float v[8];
    #pragma unroll
    for (int i = 0; i < 8; i++){
      float vv = acc[i] + b[hh * 64 + f * 8 + i];
      v[i] = vv > 0.f ? vv : 0.f;
    }
    float* op = out + (size_t)node * 256 + hh * 64 + f * 8;
    *(float4*)op       = make_float4(v[0], v[1], v[2], v[3]);
    *(float4*)(op + 4) = make_float4(v[4], v[5], v[6], v[7]);
  }
}

// ---------------- fused aggregation, mu & logstd (H=1, D=64) ----------------
// block = 128 = 2 waves; wave 0 -> mu, wave 1 -> logstd; same 8-lane/edge pass2
__global__ __launch_bounds__(128)
void gat_aggr2_k(const int* __restrict__ offs, const int* __restrict__ srcs,
                 const float* __restrict__ em, const float* __restrict__ el,
                 const bf16* __restrict__ hmu, const bf16* __restrict__ hls,
                 const float* __restrict__ bmu, const float* __restrict__ bls,
                 float* __restrict__ outmu, float* __restrict__ outls, int n){
  int node = blockIdx.x;
  if (node >= n) return;
  int wave = threadIdx.x >> 6;
  int lane = threadIdx.x & 63;
  const float* eH = wave ? el : em;
  const bf16*  h  = wave ? hls : hmu;
  const float* bb = wave ? bls : bmu;
  float* out = wave ? outls : outmu;
  int beg = offs[node], end = offs[node + 1];
  float mx = -1e30f;
  for (int j = beg + lane; j < end; j += 64) mx = fmaxf(mx, eH[j]);
  #pragma unroll
  for (int o = 32; o > 0; o >>= 1) mx = fmaxf(mx, __shfl_xor(mx, o));
  float sm = 0.f;
  for (int j = beg + lane; j < end; j += 64) sm += __expf(eH[j] - mx);
  #pragma unroll
  for (int o = 32; o > 0; o >>= 1) sm += __shfl_xor(sm, o);
  float inv = 1.f / (sm + 1e-16f);
  const int q = lane >> 3;
  const int f = lane & 7;
  float acc[8];
  #pragma unroll
  for (int i = 0; i < 8; i++) acc[i] = 0.f;
  for (int j0 = beg; j0 < end; j0 += 64){
    int nj = end - j0; if (nj > 64) nj = 64;
    float aL = 0.f; int sL = 0;
    if (lane < nj){
      sL = srcs[j0 + lane];
      aL = __expf(eH[j0 + lane] - mx) * inv;
    }
    for (int t = 0; t < nj; t += 8){
      int idx = t + q;
      float a = __shfl(aL, idx);
      int s   = __shfl(sL, idx);
      uint4 dw = *(const uint4*)(h + (size_t)s * 64 + f * 8);
      float lo, hi;
      unpack2(dw.x, lo, hi); acc[0] = fmaf(lo, a, acc[0]); acc[1] = fmaf(hi, a, acc[1]);
      unpack2(dw.y, lo, hi); acc[2] = fmaf(lo, a, acc[2]); acc[3] = fmaf(hi, a, acc[3]);
      unpack2(dw.z, lo, hi); acc[4] = fmaf(lo, a, acc[4]); acc[5] = fmaf(hi, a, acc[5]);
      unpack2(dw.w, lo, hi); acc[6] = fmaf(lo, a, acc[6]); acc[7] = fmaf(hi, a, acc[7]);
    }
  }
  #pragma unroll
  for (int o = 8; o < 64; o <<= 1){
    #pragma unroll
    for (int i = 0; i < 8; i++) acc[i] += __shfl_xor(acc[i], o);
  }
  if (lane < 8){
    float v[8];
    #pragma unroll
    for (int i = 0; i < 8; i++) v[i] = acc[i] + bb[f * 8 + i];
    float* op = out + (size_t)node * 64 + f * 8;
    *(float4*)op       = make_float4(v[0], v[1], v[2], v[3]);
    *(float4*)(op + 4) = make_float4(v[4], v[5], v[6], v[7]);
  }
}

extern "C" void kernel_launch(void* const* d_in, const int* in_sizes, int n_in,
                              void* d_out, int out_size, void* d_ws, size_t ws_size,
                              hipStream_t stream){
  const float* x    = (const float*)d_in[0];
  const int*   ei   = (const int*)d_in[1];
  const float* W1   = (const float*)d_in[2];
  const float* aS1  = (const float*)d_in[3];
  const float* aD1  = (const float*)d_in[4];
  const float* b1   = (const float*)d_in[5];
  const float* Wmu  = (const float*)d_in[6];
  const float* aSmu = (const float*)d_in[7];
  const float* aDmu = (const float*)d_in[8];
  const float* bmu  = (const float*)d_in[9];
  const float* Wls  = (const float*)d_in[10];
  const float* aSls = (const float*)d_in[11];
  const float* aDls = (const float*)d_in[12];
  const float* bls  = (const float*)d_in[13];

  const int N    = NNODES;
  const int E0   = in_sizes[1] / 2;
  const int Etot = E0 + N;

  // ---- workspace layout (float units) ----
  float* ws   = (float*)d_ws;
  float* bbuf = ws;                          // [0, 12.8M) f32 layer-1 out
  bf16*  h1bf = (bf16*)(ws + 12800000);      // [12.8M, 19.2M) 12.8M bf16
  float* e1   = ws + 19200000;               // [19.2M, 22.6M) 4*Etot f32 (dead after aggr1)
  bf16*  h2mu = (bf16*)(ws + 19200000);      // overlay on e1 after aggr1
  bf16*  h2ls = (bf16*)(ws + 20800000);
  float* e2m  = ws + 22600000;               // Etot f32
  float* e2l  = ws + 23450000;               // Etot f32
  float* as1  = ws + 24300000;               // 200K
  float* ad1  = ws + 24500000;               // 200K
  float* as2m = as1;                         // overlays, as1/ad1 dead after logit1
  float* ad2m = as1 + 50000;
  float* as2l = as1 + 100000;
  float* ad2l = as1 + 150000;
  int* cnt    = (int*)(ws + 24700000);       // 50K
  int* cursor = cnt + 50000;                 // 50K
  int* offs   = (int*)(ws + 24800000);       // 50001
  int* srcs   = offs + 50001;                // 850000
  int* dsts   = srcs + 850000;               // 850000
  int* bsums  = dsts + 850000;               // 64

  float* outmu = (float*)d_out;
  float* outls = (float*)d_out + 3200000;

  const int egrid = (Etot + 255) / 256;

  // ---- CSR build (shared by all 3 convs) ----
  hipMemsetAsync(cnt, 0, 50000 * sizeof(int), stream);
  hist_k<<<egrid, 256, 0, stream>>>(ei, E0, Etot, cnt);
  scanA_k<<<(N + 1023) / 1024, 1024, 0, stream>>>(cnt, offs, bsums, N);
  scanB_k<<<1, 64, 0, stream>>>(bsums, (N + 1023) / 1024);
  scanC_k<<<(N + 256) / 256, 256, 0, stream>>>(offs, bsums, cursor, N, Etot);
  sort_k<<<egrid, 256, 0, stream>>>(ei, E0, Etot, cursor, srcs, dsts);

  // ---- layer 1: GATConv(128 -> 4x64, concat) + bias + ReLU ----
  gemm_k<128, 256, 32><<<(N + 31) / 32, 256, 0, stream>>>(x, W1, h1bf, N);
  alpha_k<4><<<(N * 4 + 255) / 256, 256, 0, stream>>>(h1bf, aS1, aD1, as1, ad1, N);
  logit1_k<<<egrid, 256, 0, stream>>>(srcs, dsts, as1, ad1, e1, Etot);
  gat_aggr1_k<<<N, 256, 0, stream>>>(offs, srcs, e1, h1bf, b1, bbuf, N, Etot);

  // ---- layers mu & logstd: GATConv(256 -> 1x64) + bias ----
  gemm_dual_k<256, 32><<<(N + 31) / 32, 256, 0, stream>>>(bbuf, Wmu, Wls, h2mu, h2ls, N);
  alpha_k<1><<<(N + 255) / 256, 256, 0, stream>>>(h2mu, aSmu, aDmu, as2m, ad2m, N);
  alpha_k<1><<<(N + 255) / 256, 256, 0, stream>>>(h2ls, aSls, aDls, as2l, ad2l, N);
  logit2_k<<<egrid, 256, 0, stream>>>(srcs, dsts, as2m, ad2m, as2l, ad2l, e2m, e2l, Etot);
  gat_aggr2_k<<<N, 128, 0, stream>>>(offs, srcs, e2m, e2l, h2mu, h2ls,
                                     bmu, bls, outmu, outls, N);
}

// Round 6
// 353.781 us; speedup vs baseline: 5.0737x; 1.3127x over previous
//
#include <hip/hip_runtime.h>
#include <hip/hip_bf16.h>

#define NNODES 50000
#define MT 3125              // NNODES / 16 row-tiles
typedef __hip_bfloat16 bf16;
typedef __attribute__((ext_vector_type(8))) short bf16x8;  // 8 bf16 (4 VGPRs)
typedef __attribute__((ext_vector_type(4))) float f32x4;   // 4 f32 acc

__device__ __forceinline__ void unpack2(unsigned w, float& lo, float& hi){
  lo = __uint_as_float(w << 16);
  hi = __uint_as_float(w & 0xffff0000u);
}
__device__ __forceinline__ short f2bf(float f){
  union { __hip_bfloat16 h; short s; } u; u.h = __float2bfloat16(f); return u.s;
}

// ---------------- pack x[50000,128] f32 -> A-fragment bf16 ----------------
// Ap[(rt*4+kt)*64 + lane][j] = x[rt*16 + (lane&15)][kt*32 + (lane>>4)*8 + j]
__global__ __launch_bounds__(256)
void cvt_x_k(const float* __restrict__ x, bf16x8* __restrict__ Ap){
  int t = blockIdx.x * 256 + threadIdx.x;       // over MT*4*64 = 800000
  if (t >= MT * 256) return;
  int lane = t & 63;
  int kt   = (t >> 6) & 3;
  int rt   = t >> 8;
  const float* src = x + (size_t)(rt * 16 + (lane & 15)) * 128 + kt * 32 + (lane >> 4) * 8;
  float4 v0 = *(const float4*)src;
  float4 v1 = *(const float4*)(src + 4);
  bf16x8 o;
  o[0] = f2bf(v0.x); o[1] = f2bf(v0.y); o[2] = f2bf(v0.z); o[3] = f2bf(v0.w);
  o[4] = f2bf(v1.x); o[5] = f2bf(v1.y); o[6] = f2bf(v1.z); o[7] = f2bf(v1.w);
  Ap[t] = o;
}

// ---------------- pack weights -> B-fragment bf16 ----------------
// Bp1: W1[128,256]: Bp1[(kt*16+ct)*64+lane][j] = W1[kt*32+(lane>>4)*8+j][ct*16+(lane&15)]
// Bp2: [Wmu|Wls][256,128]: same with 8 kt, 8 ct
__global__ __launch_bounds__(256)
void cvt_w_k(const float* __restrict__ W1, const float* __restrict__ Wmu,
             const float* __restrict__ Wls, bf16x8* __restrict__ Bp1,
             bf16x8* __restrict__ Bp2){
  int t = blockIdx.x * 256 + threadIdx.x;
  if (t < 4096){
    int lane = t & 63, ct = (t >> 6) & 15, kt = t >> 10;
    int k0 = kt * 32 + (lane >> 4) * 8, col = ct * 16 + (lane & 15);
    bf16x8 o;
    #pragma unroll
    for (int j = 0; j < 8; j++) o[j] = f2bf(W1[(size_t)(k0 + j) * 256 + col]);
    Bp1[t] = o;
  } else if (t < 8192){
    int u = t - 4096;
    int lane = u & 63, ct = (u >> 6) & 7, kt = u >> 9;
    int k0 = kt * 32 + (lane >> 4) * 8, col = ct * 16 + (lane & 15);
    const float* W = (col < 64) ? Wmu : Wls;
    int cc = col & 63;
    bf16x8 o;
    #pragma unroll
    for (int j = 0; j < 8; j++) o[j] = f2bf(W[(size_t)(k0 + j) * 64 + cc]);
    Bp2[u] = o;
  }
}

// ---------------- MFMA GEMM 1: [50000,128] @ [128,256] -> h1bf row-major ----------------
// block = 4 waves; wave w owns cols w*64..w*64+63 (4 col-frags); K-loop 4 steps
__global__ __launch_bounds__(256)
void gemm1_mfma(const bf16x8* __restrict__ Ap, const bf16x8* __restrict__ Bp,
                bf16* __restrict__ Y){
  int rt = blockIdx.x;
  int w = threadIdx.x >> 6, lane = threadIdx.x & 63;
  f32x4 z = {0.f, 0.f, 0.f, 0.f};
  f32x4 acc[4] = {z, z, z, z};
  for (int kt = 0; kt < 4; kt++){
    bf16x8 a = Ap[(size_t)(rt * 4 + kt) * 64 + lane];
    #pragma unroll
    for (int c = 0; c < 4; c++){
      int ct = w * 4 + c;
      bf16x8 b = Bp[(size_t)(kt * 16 + ct) * 64 + lane];
      acc[c] = __builtin_amdgcn_mfma_f32_16x16x32_bf16(a, b, acc[c], 0, 0, 0);
    }
  }
  int row0 = rt * 16 + (lane >> 4) * 4;
  #pragma unroll
  for (int c = 0; c < 4; c++){
    int col = w * 64 + c * 16 + (lane & 15);
    #pragma unroll
    for (int i = 0; i < 4; i++)
      Y[(size_t)(row0 + i) * 256 + col] = __float2bfloat16(acc[c][i]);
  }
}

// ---------------- MFMA GEMM 2: [50000,256] @ [256,128] -> h2mu, h2ls ----------------
// wave w: ct = w*2..w*2+1; w<2 -> mu cols, w>=2 -> ls cols
__global__ __launch_bounds__(256)
void gemm2_mfma(const bf16x8* __restrict__ Ap, const bf16x8* __restrict__ Bp,
                bf16* __restrict__ Ymu, bf16* __restrict__ Yls){
  int rt = blockIdx.x;
  int w = threadIdx.x >> 6, lane = threadIdx.x & 63;
  f32x4 z = {0.f, 0.f, 0.f, 0.f};
  f32x4 acc[2] = {z, z};
  for (int kt = 0; kt < 8; kt++){
    bf16x8 a = Ap[(size_t)(rt * 8 + kt) * 64 + lane];
    #pragma unroll
    for (int c = 0; c < 2; c++){
      int ct = w * 2 + c;
      bf16x8 b = Bp[(size_t)(kt * 8 + ct) * 64 + lane];
      acc[c] = __builtin_amdgcn_mfma_f32_16x16x32_bf16(a, b, acc[c], 0, 0, 0);
    }
  }
  bf16* Y = (w < 2) ? Ymu : Yls;
  int row0 = rt * 16 + (lane >> 4) * 4;
  #pragma unroll
  for (int c = 0; c < 2; c++){
    int col = (w & 1) * 32 + c * 16 + (lane & 15);
    #pragma unroll
    for (int i = 0; i < 4; i++)
      Y[(size_t)(row0 + i) * 64 + col] = __float2bfloat16(acc[c][i]);
  }
}

// ---------------- per-node attention logits from bf16 h ----------------
template<int H>
__global__ __launch_bounds__(256)
void alpha_k(const bf16* __restrict__ h, const float* __restrict__ a_s,
             const float* __restrict__ a_d, float* __restrict__ os,
             float* __restrict__ od, int n){
  int i = blockIdx.x * 256 + threadIdx.x;
  if (i >= n * H) return;
  int hh = i % H;
  const uint4* hp  = (const uint4*)(h + (size_t)i * 64);
  const float* asp = a_s + hh * 64;
  const float* adp = a_d + hh * 64;
  float s1 = 0.f, s2 = 0.f;
  #pragma unroll
  for (int q = 0; q < 8; q++){
    uint4 v = hp[q];
    unsigned w[4] = {v.x, v.y, v.z, v.w};
    #pragma unroll
    for (int p = 0; p < 4; p++){
      float lo, hi; unpack2(w[p], lo, hi);
      int d = q * 8 + p * 2;
      s1 = fmaf(lo, asp[d], s1);     s2 = fmaf(lo, adp[d], s2);
      s1 = fmaf(hi, asp[d + 1], s1); s2 = fmaf(hi, adp[d + 1], s2);
    }
  }
  os[i] = s1; od[i] = s2;
}

// ---------------- CSR build ----------------
__global__ __launch_bounds__(256)
void hist_k(const int* __restrict__ ei, int E0, int Etot, int* __restrict__ cnt){
  int e = blockIdx.x * 256 + threadIdx.x;
  if (e >= Etot) return;
  int d = (e < E0) ? ei[E0 + e] : e - E0;
  atomicAdd(&cnt[d], 1);
}

__global__ __launch_bounds__(1024)
void scanA_k(const int* __restrict__ cnt, int* __restrict__ offs,
             int* __restrict__ bsums, int n){
  __shared__ int buf[1024];
  int tid = threadIdx.x;
  int i = blockIdx.x * 1024 + tid;
  int v = (i < n) ? cnt[i] : 0;
  buf[tid] = v; __syncthreads();
  int acc = v;
  for (int off = 1; off < 1024; off <<= 1){
    int t = (tid >= off) ? buf[tid - off] : 0;
    __syncthreads();
    acc += t; buf[tid] = acc;
    __syncthreads();
  }
  if (i < n) offs[i] = acc - v;
  if (tid == 1023) bsums[blockIdx.x] = acc;
}

__global__ void scanB_k(int* __restrict__ bsums, int nb){
  if (threadIdx.x == 0 && blockIdx.x == 0){
    int run = 0;
    for (int i = 0; i < nb; i++){ int t = bsums[i]; bsums[i] = run; run += t; }
  }
}

__global__ __launch_bounds__(256)
void scanC_k(int* __restrict__ offs, const int* __restrict__ bsums,
             int* __restrict__ cursor, int n, int total){
  int i = blockIdx.x * 256 + threadIdx.x;
  if (i < n){
    int v = offs[i] + bsums[i >> 10];
    offs[i] = v;
    cursor[i] = v;
  }
  if (i == 0) offs[n] = total;
}

__global__ __launch_bounds__(256)
void sort_k(const int* __restrict__ ei, int E0, int Etot,
            int* __restrict__ cursor, int* __restrict__ srcs,
            int* __restrict__ dsts){
  int e = blockIdx.x * 256 + threadIdx.x;
  if (e >= Etot) return;
  int s, d;
  if (e < E0){ s = ei[e]; d = ei[E0 + e]; } else { s = d = e - E0; }
  int pos = atomicAdd(&cursor[d], 1);
  srcs[pos] = s;
  dsts[pos] = d;
}

// ---------------- edge-parallel logits (leaky applied), SoA by head ----------------
__global__ __launch_bounds__(256)
void logit1_k(const int* __restrict__ srcs, const int* __restrict__ dsts,
              const float* __restrict__ as, const float* __restrict__ ad,
              float* __restrict__ e1, int Etot){
  int j = blockIdx.x * 256 + threadIdx.x;
  if (j >= Etot) return;
  int s = srcs[j], d = dsts[j];
  float4 av = *(const float4*)(as + s * 4);
  float4 dv = *(const float4*)(ad + d * 4);
  float e0 = av.x + dv.x; e0 = e0 > 0.f ? e0 : 0.2f * e0;
  float e1v = av.y + dv.y; e1v = e1v > 0.f ? e1v : 0.2f * e1v;
  float e2 = av.z + dv.z; e2 = e2 > 0.f ? e2 : 0.2f * e2;
  float e3 = av.w + dv.w; e3 = e3 > 0.f ? e3 : 0.2f * e3;
  e1[j] = e0; e1[Etot + j] = e1v; e1[2 * Etot + j] = e2; e1[3 * Etot + j] = e3;
}

__global__ __launch_bounds__(256)
void logit2_k(const int* __restrict__ srcs, const int* __restrict__ dsts,
              const float* __restrict__ asm_, const float* __restrict__ adm,
              const float* __restrict__ asl, const float* __restrict__ adl,
              float* __restrict__ em, float* __restrict__ el, int Etot){
  int j = blockIdx.x * 256 + threadIdx.x;
  if (j >= Etot) return;
  int s = srcs[j], d = dsts[j];
  float a = asm_[s] + adm[d]; a = a > 0.f ? a : 0.2f * a;
  float b = asl[s] + adl[d]; b = b > 0.f ? b : 0.2f * b;
  em[j] = a; el[j] = b;
}

// ---------------- fused aggregation, layer 1 (H=4, D=64) ----------------
// writes layer-1 output (bias+ReLU) DIRECTLY in packed A-fragment bf16 layout
__global__ __launch_bounds__(256)
void gat_aggr1_k(const int* __restrict__ offs, const int* __restrict__ srcs,
                 const float* __restrict__ e1, const bf16* __restrict__ h,
                 const float* __restrict__ b, bf16x8* __restrict__ Ap2,
                 int n, int Etot){
  int node = blockIdx.x;
  if (node >= n) return;
  int hh   = threadIdx.x >> 6;
  int lane = threadIdx.x & 63;
  int beg = offs[node], end = offs[node + 1];
  const float* eH = e1 + (size_t)hh * Etot;
  float mx = -1e30f;
  for (int j = beg + lane; j < end; j += 64) mx = fmaxf(mx, eH[j]);
  #pragma unroll
  for (int o = 32; o > 0; o >>= 1) mx = fmaxf(mx, __shfl_xor(mx, o));
  float sm = 0.f;
  for (int j = beg + lane; j < end; j += 64) sm += __expf(eH[j] - mx);
  #pragma unroll
  for (int o = 32; o > 0; o >>= 1) sm += __shfl_xor(sm, o);
  float inv = 1.f / (sm + 1e-16f);
  const int q = lane >> 3;   // edge slot
  const int f = lane & 7;    // feature octet
  float acc[8];
  #pragma unroll
  for (int i = 0; i < 8; i++) acc[i] = 0.f;
  for (int j0 = beg; j0 < end; j0 += 64){
    int nj = end - j0; if (nj > 64) nj = 64;
    float aL = 0.f; int sL = 0;
    if (lane < nj){
      sL = srcs[j0 + lane];
      aL = __expf(eH[j0 + lane] - mx) * inv;
    }
    for (int t = 0; t < nj; t += 8){
      int idx = t + q;
      float a = __shfl(aL, idx);
      int s   = __shfl(sL, idx);
      uint4 dw = *(const uint4*)(h + (size_t)s * 256 + hh * 64 + f * 8);
      float lo, hi;
      unpack2(dw.x, lo, hi); acc[0] = fmaf(lo, a, acc[0]); acc[1] = fmaf(hi, a, acc[1]);
      unpack2(dw.y, lo, hi); acc[2] = fmaf(lo, a, acc[2]); acc[3] = fmaf(hi, a, acc[3]);
      unpack2(dw.z, lo, hi); acc[4] = fmaf(lo, a, acc[4]); acc[5] = fmaf(hi, a, acc[5]);
      unpack2(dw.w, lo, hi); acc[6] = fmaf(lo, a, acc[6]); acc[7] = fmaf(hi, a, acc[7]);
    }
  }
  #pragma unroll
  for (int o = 8; o < 64; o <<= 1){
    #pragma unroll
    for (int i = 0; i < 8; i++) acc[i] += __shfl_xor(acc[i], o);
  }
  if (lane < 8){
    // packed A-frag slot: k = O*8+i where O = hh*8+lane; row = node
    int O = hh * 8 + lane;
    int kt = O >> 2, g = O & 3;
    int rt = node >> 4, r = node & 15;
    bf16x8 o;
    #pragma unroll
    for (int i = 0; i < 8; i++){
      float vv = acc[i] + b[hh * 64 + lane * 8 + i];
      o[i] = f2bf(vv > 0.f ? vv : 0.f);
    }
    Ap2[(size_t)(rt * 8 + kt) * 64 + g * 16 + r] = o;
  }
}

// ---------------- fused aggregation, mu & logstd (H=1, D=64) ----------------
__global__ __launch_bounds__(128)
void gat_aggr2_k(const int* __restrict__ offs, const int* __restrict__ srcs,
                 const float* __restrict__ em, const float* __restrict__ el,
                 const bf16* __restrict__ hmu, const bf16* __restrict__ hls,
                 const float* __restrict__ bmu, const float* __restrict__ bls,
                 float* __restrict__ outmu, float* __restrict__ outls, int n){
  int node = blockIdx.x;
  if (node >= n) return;
  int wave = threadIdx.x >> 6;
  int lane = threadIdx.x & 63;
  const float* eH = wave ? el : em;
  const bf16*  h  = wave ? hls : hmu;
  const float* bb = wave ? bls : bmu;
  float* out = wave ? outls : outmu;
  int beg = offs[node], end = offs[node + 1];
  float mx = -1e30f;
  for (int j = beg + lane; j < end; j += 64) mx = fmaxf(mx, eH[j]);
  #pragma unroll
  for (int o = 32; o > 0; o >>= 1) mx = fmaxf(mx, __shfl_xor(mx, o));
  float sm = 0.f;
  for (int j = beg + lane; j < end; j += 64) sm += __expf(eH[j] - mx);
  #pragma unroll
  for (int o = 32; o > 0; o >>= 1) sm += __shfl_xor(sm, o);
  float inv = 1.f / (sm + 1e-16f);
  const int q = lane >> 3;
  const int f = lane & 7;
  float acc[8];
  #pragma unroll
  for (int i = 0; i < 8; i++) acc[i] = 0.f;
  for (int j0 = beg; j0 < end; j0 += 64){
    int nj = end - j0; if (nj > 64) nj = 64;
    float aL = 0.f; int sL = 0;
    if (lane < nj){
      sL = srcs[j0 + lane];
      aL = __expf(eH[j0 + lane] - mx) * inv;
    }
    for (int t = 0; t < nj; t += 8){
      int idx = t + q;
      float a = __shfl(aL, idx);
      int s   = __shfl(sL, idx);
      uint4 dw = *(const uint4*)(h + (size_t)s * 64 + f * 8);
      float lo, hi;
      unpack2(dw.x, lo, hi); acc[0] = fmaf(lo, a, acc[0]); acc[1] = fmaf(hi, a, acc[1]);
      unpack2(dw.y, lo, hi); acc[2] = fmaf(lo, a, acc[2]); acc[3] = fmaf(hi, a, acc[3]);
      unpack2(dw.z, lo, hi); acc[4] = fmaf(lo, a, acc[4]); acc[5] = fmaf(hi, a, acc[5]);
      unpack2(dw.w, lo, hi); acc[6] = fmaf(lo, a, acc[6]); acc[7] = fmaf(hi, a, acc[7]);
    }
  }
  #pragma unroll
  for (int o = 8; o < 64; o <<= 1){
    #pragma unroll
    for (int i = 0; i < 8; i++) acc[i] += __shfl_xor(acc[i], o);
  }
  if (lane < 8){
    float v[8];
    #pragma unroll
    for (int i = 0; i < 8; i++) v[i] = acc[i] + bb[f * 8 + i];
    float* op = out + (size_t)node * 64 + f * 8;
    *(float4*)op       = make_float4(v[0], v[1], v[2], v[3]);
    *(float4*)(op + 4) = make_float4(v[4], v[5], v[6], v[7]);
  }
}

extern "C" void kernel_launch(void* const* d_in, const int* in_sizes, int n_in,
                              void* d_out, int out_size, void* d_ws, size_t ws_size,
                              hipStream_t stream){
  const float* x    = (const float*)d_in[0];
  const int*   ei   = (const int*)d_in[1];
  const float* W1   = (const float*)d_in[2];
  const float* aS1  = (const float*)d_in[3];
  const float* aD1  = (const float*)d_in[4];
  const float* b1   = (const float*)d_in[5];
  const float* Wmu  = (const float*)d_in[6];
  const float* aSmu = (const float*)d_in[7];
  const float* aDmu = (const float*)d_in[8];
  const float* bmu  = (const float*)d_in[9];
  const float* Wls  = (const float*)d_in[10];
  const float* aSls = (const float*)d_in[11];
  const float* aDls = (const float*)d_in[12];
  const float* bls  = (const float*)d_in[13];

  const int N    = NNODES;
  const int E0   = in_sizes[1] / 2;
  const int Etot = E0 + N;

  // ---- workspace layout (float-unit offsets; all bf16x8 arrays 16B-aligned) ----
  float* ws = (float*)d_ws;
  bf16x8* Ap2  = (bf16x8*)(ws);                 // [0, 6.4M): layer-1 out, packed A-frag
  bf16*   h1bf = (bf16*)(ws + 6400000);         // [6.4M, 12.8M): 12.8M bf16 row-major
  bf16x8* Ap1  = (bf16x8*)(ws + 12800000);      // [12.8M, 16.0M): x packed
  float*  e1   = ws + 16000000;                 // [16M, 19.4M): 4*Etot (dead after aggr1)
  bf16*   h2mu = (bf16*)(ws + 16000000);        // overlay on e1 after aggr1
  bf16*   h2ls = (bf16*)(ws + 17600000);
  float*  e2m  = ws + 19400000;                 // Etot
  float*  e2l  = ws + 20250000;                 // Etot
  float*  as1  = ws + 21100000;                 // 200K
  float*  ad1  = ws + 21300000;                 // 200K
  float*  as2m = as1;                           // overlays (as1/ad1 dead after logit1)
  float*  ad2m = as1 + 50000;
  float*  as2l = as1 + 100000;
  float*  ad2l = as1 + 150000;
  int* cnt    = (int*)(ws + 21500000);          // 50K
  int* cursor = (int*)(ws + 21550000);          // 50K
  int* offs   = (int*)(ws + 21600000);          // 50001
  int* srcs   = (int*)(ws + 21650016);          // 850K
  int* dsts   = (int*)(ws + 22500016);          // 850K
  int* bsums  = (int*)(ws + 23350016);          // 64
  bf16x8* Bp1 = (bf16x8*)(ws + 23350080);       // 32768 bf16
  bf16x8* Bp2 = (bf16x8*)(ws + 23366464);       // 32768 bf16

  float* outmu = (float*)d_out;
  float* outls = (float*)d_out + 3200000;

  const int egrid = (Etot + 255) / 256;

  // ---- CSR build (shared by all 3 convs) ----
  hipMemsetAsync(cnt, 0, 50000 * sizeof(int), stream);
  hist_k<<<egrid, 256, 0, stream>>>(ei, E0, Etot, cnt);
  scanA_k<<<(N + 1023) / 1024, 1024, 0, stream>>>(cnt, offs, bsums, N);
  scanB_k<<<1, 64, 0, stream>>>(bsums, (N + 1023) / 1024);
  scanC_k<<<(N + 256) / 256, 256, 0, stream>>>(offs, bsums, cursor, N, Etot);
  sort_k<<<egrid, 256, 0, stream>>>(ei, E0, Etot, cursor, srcs, dsts);

  // ---- weight/input packing for MFMA ----
  cvt_w_k<<<32, 256, 0, stream>>>(W1, Wmu, Wls, Bp1, Bp2);
  cvt_x_k<<<MT, 256, 0, stream>>>(x, Ap1);

  // ---- layer 1: GATConv(128 -> 4x64, concat) + bias + ReLU ----
  gemm1_mfma<<<MT, 256, 0, stream>>>(Ap1, Bp1, h1bf);
  alpha_k<4><<<(N * 4 + 255) / 256, 256, 0, stream>>>(h1bf, aS1, aD1, as1, ad1, N);
  logit1_k<<<egrid, 256, 0, stream>>>(srcs, dsts, as1, ad1, e1, Etot);
  gat_aggr1_k<<<N, 256, 0, stream>>>(offs, srcs, e1, h1bf, b1, Ap2, N, Etot);

  // ---- layers mu & logstd: GATConv(256 -> 1x64) + bias ----
  gemm2_mfma<<<MT, 256, 0, stream>>>(Ap2, Bp2, h2mu, h2ls);
  alpha_k<1><<<(N + 255) / 256, 256, 0, stream>>>(h2mu, aSmu, aDmu, as2m, ad2m, N);
  alpha_k<1><<<(N + 255) / 256, 256, 0, stream>>>(h2ls, aSls, aDls, as2l, ad2l, N);
  logit2_k<<<egrid, 256, 0, stream>>>(srcs, dsts, as2m, ad2m, as2l, ad2l, e2m, e2l, Etot);
  gat_aggr2_k<<<N, 128, 0, stream>>>(offs, srcs, e2m, e2l, h2mu, h2ls,
                                     bmu, bls, outmu, outls, N);
}

// Round 7
// 315.762 us; speedup vs baseline: 5.6846x; 1.1204x over previous
//
#include <hip/hip_runtime.h>
#include <hip/hip_bf16.h>

#define NNODES 50000
#define MT 3125              // NNODES / 16 row-tiles
typedef __hip_bfloat16 bf16;
typedef __attribute__((ext_vector_type(8))) short bf16x8;  // 8 bf16 (4 VGPRs)
typedef __attribute__((ext_vector_type(4))) float f32x4;   // 4 f32 acc

__device__ __forceinline__ void unpack2(unsigned w, float& lo, float& hi){
  lo = __uint_as_float(w << 16);
  hi = __uint_as_float(w & 0xffff0000u);
}
__device__ __forceinline__ short f2bf(float f){
  union { __hip_bfloat16 h; short s; } u; u.h = __float2bfloat16(f); return u.s;
}

// ---------------- pack x[50000,128] f32 -> A-fragment bf16 ----------------
__global__ __launch_bounds__(256)
void cvt_x_k(const float* __restrict__ x, bf16x8* __restrict__ Ap){
  int t = blockIdx.x * 256 + threadIdx.x;
  if (t >= MT * 256) return;
  int lane = t & 63;
  int kt   = (t >> 6) & 3;
  int rt   = t >> 8;
  const float* src = x + (size_t)(rt * 16 + (lane & 15)) * 128 + kt * 32 + (lane >> 4) * 8;
  float4 v0 = *(const float4*)src;
  float4 v1 = *(const float4*)(src + 4);
  bf16x8 o;
  o[0] = f2bf(v0.x); o[1] = f2bf(v0.y); o[2] = f2bf(v0.z); o[3] = f2bf(v0.w);
  o[4] = f2bf(v1.x); o[5] = f2bf(v1.y); o[6] = f2bf(v1.z); o[7] = f2bf(v1.w);
  Ap[t] = o;
}

// ---------------- pack weights -> B-fragment bf16 ----------------
__global__ __launch_bounds__(256)
void cvt_w_k(const float* __restrict__ W1, const float* __restrict__ Wmu,
             const float* __restrict__ Wls, bf16x8* __restrict__ Bp1,
             bf16x8* __restrict__ Bp2){
  int t = blockIdx.x * 256 + threadIdx.x;
  if (t < 4096){
    int lane = t & 63, ct = (t >> 6) & 15, kt = t >> 10;
    int k0 = kt * 32 + (lane >> 4) * 8, col = ct * 16 + (lane & 15);
    bf16x8 o;
    #pragma unroll
    for (int j = 0; j < 8; j++) o[j] = f2bf(W1[(size_t)(k0 + j) * 256 + col]);
    Bp1[t] = o;
  } else if (t < 8192){
    int u = t - 4096;
    int lane = u & 63, ct = (u >> 6) & 7, kt = u >> 9;
    int k0 = kt * 32 + (lane >> 4) * 8, col = ct * 16 + (lane & 15);
    const float* W = (col < 64) ? Wmu : Wls;
    int cc = col & 63;
    bf16x8 o;
    #pragma unroll
    for (int j = 0; j < 8; j++) o[j] = f2bf(W[(size_t)(k0 + j) * 64 + cc]);
    Bp2[u] = o;
  }
}

// ---------------- MFMA GEMM 1: [50000,128] @ [128,256] -> h1bf row-major ----------------
__global__ __launch_bounds__(256)
void gemm1_mfma(const bf16x8* __restrict__ Ap, const bf16x8* __restrict__ Bp,
                bf16* __restrict__ Y){
  int rt = blockIdx.x;
  int w = threadIdx.x >> 6, lane = threadIdx.x & 63;
  f32x4 z = {0.f, 0.f, 0.f, 0.f};
  f32x4 acc[4] = {z, z, z, z};
  for (int kt = 0; kt < 4; kt++){
    bf16x8 a = Ap[(size_t)(rt * 4 + kt) * 64 + lane];
    #pragma unroll
    for (int c = 0; c < 4; c++){
      int ct = w * 4 + c;
      bf16x8 b = Bp[(size_t)(kt * 16 + ct) * 64 + lane];
      acc[c] = __builtin_amdgcn_mfma_f32_16x16x32_bf16(a, b, acc[c], 0, 0, 0);
    }
  }
  int row0 = rt * 16 + (lane >> 4) * 4;
  #pragma unroll
  for (int c = 0; c < 4; c++){
    int col = w * 64 + c * 16 + (lane & 15);
    #pragma unroll
    for (int i = 0; i < 4; i++)
      Y[(size_t)(row0 + i) * 256 + col] = __float2bfloat16(acc[c][i]);
  }
}

// ---------------- MFMA GEMM 2: [50000,256] @ [256,128] -> h2mu, h2ls ----------------
__global__ __launch_bounds__(256)
void gemm2_mfma(const bf16x8* __restrict__ Ap, const bf16x8* __restrict__ Bp,
                bf16* __restrict__ Ymu, bf16* __restrict__ Yls){
  int rt = blockIdx.x;
  int w = threadIdx.x >> 6, lane = threadIdx.x & 63;
  f32x4 z = {0.f, 0.f, 0.f, 0.f};
  f32x4 acc[2] = {z, z};
  for (int kt = 0; kt < 8; kt++){
    bf16x8 a = Ap[(size_t)(rt * 8 + kt) * 64 + lane];
    #pragma unroll
    for (int c = 0; c < 2; c++){
      int ct = w * 2 + c;
      bf16x8 b = Bp[(size_t)(kt * 8 + ct) * 64 + lane];
      acc[c] = __builtin_amdgcn_mfma_f32_16x16x32_bf16(a, b, acc[c], 0, 0, 0);
    }
  }
  bf16* Y = (w < 2) ? Ymu : Yls;
  int row0 = rt * 16 + (lane >> 4) * 4;
  #pragma unroll
  for (int c = 0; c < 2; c++){
    int col = (w & 1) * 32 + c * 16 + (lane & 15);
    #pragma unroll
    for (int i = 0; i < 4; i++)
      Y[(size_t)(row0 + i) * 64 + col] = __float2bfloat16(acc[c][i]);
  }
}

// ---------------- per-node attention logits from bf16 h ----------------
template<int H>
__global__ __launch_bounds__(256)
void alpha_k(const bf16* __restrict__ h, const float* __restrict__ a_s,
             const float* __restrict__ a_d, float* __restrict__ os,
             float* __restrict__ od, int n){
  int i = blockIdx.x * 256 + threadIdx.x;
  if (i >= n * H) return;
  int hh = i % H;
  const uint4* hp  = (const uint4*)(h + (size_t)i * 64);
  const float* asp = a_s + hh * 64;
  const float* adp = a_d + hh * 64;
  float s1 = 0.f, s2 = 0.f;
  #pragma unroll
  for (int q = 0; q < 8; q++){
    uint4 v = hp[q];
    unsigned w[4] = {v.x, v.y, v.z, v.w};
    #pragma unroll
    for (int p = 0; p < 4; p++){
      float lo, hi; unpack2(w[p], lo, hi);
      int d = q * 8 + p * 2;
      s1 = fmaf(lo, asp[d], s1);     s2 = fmaf(lo, adp[d], s2);
      s1 = fmaf(hi, asp[d + 1], s1); s2 = fmaf(hi, adp[d + 1], s2);
    }
  }
  os[i] = s1; od[i] = s2;
}

// ---------------- CSR build ----------------
__global__ __launch_bounds__(256)
void hist_k(const int* __restrict__ ei, int E0, int Etot, int* __restrict__ cnt){
  int e = blockIdx.x * 256 + threadIdx.x;
  if (e >= Etot) return;
  int d = (e < E0) ? ei[E0 + e] : e - E0;
  atomicAdd(&cnt[d], 1);
}

__global__ __launch_bounds__(1024)
void scanA_k(const int* __restrict__ cnt, int* __restrict__ offs,
             int* __restrict__ bsums, int n){
  __shared__ int buf[1024];
  int tid = threadIdx.x;
  int i = blockIdx.x * 1024 + tid;
  int v = (i < n) ? cnt[i] : 0;
  buf[tid] = v; __syncthreads();
  int acc = v;
  for (int off = 1; off < 1024; off <<= 1){
    int t = (tid >= off) ? buf[tid - off] : 0;
    __syncthreads();
    acc += t; buf[tid] = acc;
    __syncthreads();
  }
  if (i < n) offs[i] = acc - v;
  if (tid == 1023) bsums[blockIdx.x] = acc;
}

// single-wave shfl scan over <=64 block sums (replaces serial loop)
__global__ void scanB_k(int* __restrict__ bsums, int nb){
  int lane = threadIdx.x;
  int orig = (lane < nb) ? bsums[lane] : 0;
  int v = orig;
  #pragma unroll
  for (int o = 1; o < 64; o <<= 1){
    int t = __shfl_up(v, o);
    if (lane >= o) v += t;
  }
  if (lane < nb) bsums[lane] = v - orig;   // exclusive
}

__global__ __launch_bounds__(256)
void scanC_k(int* __restrict__ offs, const int* __restrict__ bsums,
             int* __restrict__ cursor, int n, int total){
  int i = blockIdx.x * 256 + threadIdx.x;
  if (i < n){
    int v = offs[i] + bsums[i >> 10];
    offs[i] = v;
    cursor[i] = v;
  }
  if (i == 0) offs[n] = total;
}

__global__ __launch_bounds__(256)
void sort_k(const int* __restrict__ ei, int E0, int Etot,
            int* __restrict__ cursor, int* __restrict__ srcs,
            int* __restrict__ dsts){
  int e = blockIdx.x * 256 + threadIdx.x;
  if (e >= Etot) return;
  int s, d;
  if (e < E0){ s = ei[e]; d = ei[E0 + e]; } else { s = d = e - E0; }
  int pos = atomicAdd(&cursor[d], 1);
  srcs[pos] = s;
  dsts[pos] = d;
}

// ---------------- edge-parallel logits (leaky applied), SoA by head ----------------
__global__ __launch_bounds__(256)
void logit1_k(const int* __restrict__ srcs, const int* __restrict__ dsts,
              const float* __restrict__ as, const float* __restrict__ ad,
              float* __restrict__ e1, int Etot){
  int j = blockIdx.x * 256 + threadIdx.x;
  if (j >= Etot) return;
  int s = srcs[j], d = dsts[j];
  float4 av = *(const float4*)(as + s * 4);
  float4 dv = *(const float4*)(ad + d * 4);
  float e0 = av.x + dv.x; e0 = e0 > 0.f ? e0 : 0.2f * e0;
  float e1v = av.y + dv.y; e1v = e1v > 0.f ? e1v : 0.2f * e1v;
  float e2 = av.z + dv.z; e2 = e2 > 0.f ? e2 : 0.2f * e2;
  float e3 = av.w + dv.w; e3 = e3 > 0.f ? e3 : 0.2f * e3;
  e1[j] = e0; e1[Etot + j] = e1v; e1[2 * Etot + j] = e2; e1[3 * Etot + j] = e3;
}

__global__ __launch_bounds__(256)
void logit2_k(const int* __restrict__ srcs, const int* __restrict__ dsts,
              const float* __restrict__ asm_, const float* __restrict__ adm,
              const float* __restrict__ asl, const float* __restrict__ adl,
              float* __restrict__ em, float* __restrict__ el, int Etot){
  int j = blockIdx.x * 256 + threadIdx.x;
  if (j >= Etot) return;
  int s = srcs[j], d = dsts[j];
  float a = asm_[s] + adm[d]; a = a > 0.f ? a : 0.2f * a;
  float b = asl[s] + adl[d]; b = b > 0.f ? b : 0.2f * b;
  em[j] = a; el[j] = b;
}

// ---------------- fused aggregation, layer 1: ONE WAVE PER NODE, all 4 heads ----------------
// passA/B: 16 lanes/head. pass2: 2 edge-slots x 4 heads x 8 octets; alpha recomputed
// per-lane (broadcast loads), no shfl distribution. Output packed A-frag + bias + ReLU.
__global__ __launch_bounds__(256)
void gat_aggr1_k(const int* __restrict__ offs, const int* __restrict__ srcs,
                 const float* __restrict__ e1, const bf16* __restrict__ h,
                 const float* __restrict__ b, bf16x8* __restrict__ Ap2,
                 int n, int Etot){
  int node = blockIdx.x * 4 + (threadIdx.x >> 6);
  if (node >= n) return;
  int lane = threadIdx.x & 63;
  int beg = offs[node], end = offs[node + 1];
  // pass A/B: head = lane>>4, idx = lane&15
  const float* eA = e1 + (size_t)(lane >> 4) * Etot;
  int iA = lane & 15;
  float mx = -1e30f;
  for (int j = beg + iA; j < end; j += 16) mx = fmaxf(mx, eA[j]);
  #pragma unroll
  for (int o = 1; o < 16; o <<= 1) mx = fmaxf(mx, __shfl_xor(mx, o));
  float sm = 0.f;
  for (int j = beg + iA; j < end; j += 16) sm += __expf(eA[j] - mx);
  #pragma unroll
  for (int o = 1; o < 16; o <<= 1) sm += __shfl_xor(sm, o);
  float inv = 1.f / (sm + 1e-16f);
  // pass 2 layout: slot = lane>>5, head = (lane>>3)&3, octet = lane&7
  int hP   = (lane >> 3) & 3;
  int oct  = lane & 7;
  int slot = lane >> 5;
  float mxP  = __shfl(mx, hP * 16);
  float invP = __shfl(inv, hP * 16);
  const float* eP = e1 + (size_t)hP * Etot;
  float acc[8];
  #pragma unroll
  for (int i = 0; i < 8; i++) acc[i] = 0.f;
  #pragma unroll 2
  for (int j0 = beg; j0 < end; j0 += 2){
    int j = j0 + slot;
    bool val = j < end;
    int s   = val ? srcs[j] : 0;
    float a = val ? __expf(eP[j] - mxP) * invP : 0.f;
    uint4 dw = *(const uint4*)(h + (size_t)s * 256 + hP * 64 + oct * 8);
    float lo, hi;
    unpack2(dw.x, lo, hi); acc[0] = fmaf(lo, a, acc[0]); acc[1] = fmaf(hi, a, acc[1]);
    unpack2(dw.y, lo, hi); acc[2] = fmaf(lo, a, acc[2]); acc[3] = fmaf(hi, a, acc[3]);
    unpack2(dw.z, lo, hi); acc[4] = fmaf(lo, a, acc[4]); acc[5] = fmaf(hi, a, acc[5]);
    unpack2(dw.w, lo, hi); acc[6] = fmaf(lo, a, acc[6]); acc[7] = fmaf(hi, a, acc[7]);
  }
  #pragma unroll
  for (int i = 0; i < 8; i++) acc[i] += __shfl_xor(acc[i], 32);
  if (lane < 32){
    // O = hP*8+oct = lane; feature = lane*8+i; packed A-frag slot
    bf16x8 o;
    #pragma unroll
    for (int i = 0; i < 8; i++){
      float vv = acc[i] + b[lane * 8 + i];
      o[i] = f2bf(vv > 0.f ? vv : 0.f);
    }
    int kt = lane >> 2, g = lane & 3;
    int rt = node >> 4, r = node & 15;
    Ap2[(size_t)(rt * 8 + kt) * 64 + g * 16 + r] = o;
  }
}

// ---------------- fused aggregation, mu & logstd: ONE WAVE PER NODE ----------------
// passA/B: 32 lanes/branch. pass2: 4 slots x 2 branches x 8 octets.
__global__ __launch_bounds__(256)
void gat_aggr2_k(const int* __restrict__ offs, const int* __restrict__ srcs,
                 const float* __restrict__ em, const float* __restrict__ el,
                 const bf16* __restrict__ hmu, const bf16* __restrict__ hls,
                 const float* __restrict__ bmu, const float* __restrict__ bls,
                 float* __restrict__ outmu, float* __restrict__ outls, int n){
  int node = blockIdx.x * 4 + (threadIdx.x >> 6);
  if (node >= n) return;
  int lane = threadIdx.x & 63;
  int beg = offs[node], end = offs[node + 1];
  // pass A/B: branch = lane>>5, idx = lane&31
  const float* eA = (lane >= 32) ? el : em;
  int iA = lane & 31;
  float mx = -1e30f;
  for (int j = beg + iA; j < end; j += 32) mx = fmaxf(mx, eA[j]);
  #pragma unroll
  for (int o = 1; o < 32; o <<= 1) mx = fmaxf(mx, __shfl_xor(mx, o));
  float sm = 0.f;
  for (int j = beg + iA; j < end; j += 32) sm += __expf(eA[j] - mx);
  #pragma unroll
  for (int o = 1; o < 32; o <<= 1) sm += __shfl_xor(sm, o);
  float inv = 1.f / (sm + 1e-16f);
  // pass 2: slot = lane>>4, branch = (lane>>3)&1, octet = lane&7
  int br   = (lane >> 3) & 1;
  int oct  = lane & 7;
  int slot = lane >> 4;
  float mxP  = __shfl(mx, br * 32);
  float invP = __shfl(inv, br * 32);
  const float* eP = br ? el : em;
  const bf16*  hP = br ? hls : hmu;
  float acc[8];
  #pragma unroll
  for (int i = 0; i < 8; i++) acc[i] = 0.f;
  #pragma unroll 2
  for (int j0 = beg; j0 < end; j0 += 4){
    int j = j0 + slot;
    bool val = j < end;
    int s   = val ? srcs[j] : 0;
    float a = val ? __expf(eP[j] - mxP) * invP : 0.f;
    uint4 dw = *(const uint4*)(hP + (size_t)s * 64 + oct * 8);
    float lo, hi;
    unpack2(dw.x, lo, hi); acc[0] = fmaf(lo, a, acc[0]); acc[1] = fmaf(hi, a, acc[1]);
    unpack2(dw.y, lo, hi); acc[2] = fmaf(lo, a, acc[2]); acc[3] = fmaf(hi, a, acc[3]);
    unpack2(dw.z, lo, hi); acc[4] = fmaf(lo, a, acc[4]); acc[5] = fmaf(hi, a, acc[5]);
    unpack2(dw.w, lo, hi); acc[6] = fmaf(lo, a, acc[6]); acc[7] = fmaf(hi, a, acc[7]);
  }
  #pragma unroll
  for (int i = 0; i < 8; i++){
    acc[i] += __shfl_xor(acc[i], 16);
    acc[i] += __shfl_xor(acc[i], 32);
  }
  if (lane < 16){
    const float* bb = (lane >= 8) ? bls : bmu;
    float* out = (lane >= 8) ? outls : outmu;
    float v[8];
    #pragma unroll
    for (int i = 0; i < 8; i++) v[i] = acc[i] + bb[oct * 8 + i];
    float* op = out + (size_t)node * 64 + oct * 8;
    *(float4*)op       = make_float4(v[0], v[1], v[2], v[3]);
    *(float4*)(op + 4) = make_float4(v[4], v[5], v[6], v[7]);
  }
}

extern "C" void kernel_launch(void* const* d_in, const int* in_sizes, int n_in,
                              void* d_out, int out_size, void* d_ws, size_t ws_size,
                              hipStream_t stream){
  const float* x    = (const float*)d_in[0];
  const int*   ei   = (const int*)d_in[1];
  const float* W1   = (const float*)d_in[2];
  const float* aS1  = (const float*)d_in[3];
  const float* aD1  = (const float*)d_in[4];
  const float* b1   = (const float*)d_in[5];
  const float* Wmu  = (const float*)d_in[6];
  const float* aSmu = (const float*)d_in[7];
  const float* aDmu = (const float*)d_in[8];
  const float* bmu  = (const float*)d_in[9];
  const float* Wls  = (const float*)d_in[10];
  const float* aSls = (const float*)d_in[11];
  const float* aDls = (const float*)d_in[12];
  const float* bls  = (const float*)d_in[13];

  const int N    = NNODES;
  const int E0   = in_sizes[1] / 2;
  const int Etot = E0 + N;

  // ---- workspace layout (float-unit offsets; bf16x8 arrays 16B-aligned) ----
  float* ws = (float*)d_ws;
  bf16x8* Ap2  = (bf16x8*)(ws);                 // [0, 6.4M): layer-1 out, packed A-frag
  bf16*   h1bf = (bf16*)(ws + 6400000);         // [6.4M, 12.8M): 12.8M bf16 row-major
  bf16x8* Ap1  = (bf16x8*)(ws + 12800000);      // [12.8M, 16.0M): x packed
  float*  e1   = ws + 16000000;                 // [16M, 19.4M): 4*Etot (dead after aggr1)
  bf16*   h2mu = (bf16*)(ws + 16000000);        // overlay on e1 after aggr1
  bf16*   h2ls = (bf16*)(ws + 17600000);
  float*  e2m  = ws + 19400000;                 // Etot
  float*  e2l  = ws + 20250000;                 // Etot
  float*  as1  = ws + 21100000;                 // 200K
  float*  ad1  = ws + 21300000;                 // 200K
  float*  as2m = as1;                           // overlays (as1/ad1 dead after logit1)
  float*  ad2m = as1 + 50000;
  float*  as2l = as1 + 100000;
  float*  ad2l = as1 + 150000;
  int* cnt    = (int*)(ws + 21500000);          // 50K
  int* cursor = (int*)(ws + 21550000);          // 50K
  int* offs   = (int*)(ws + 21600000);          // 50001
  int* srcs   = (int*)(ws + 21650016);          // 850K
  int* dsts   = (int*)(ws + 22500016);          // 850K
  int* bsums  = (int*)(ws + 23350016);          // 64
  bf16x8* Bp1 = (bf16x8*)(ws + 23350080);       // 32768 bf16
  bf16x8* Bp2 = (bf16x8*)(ws + 23366464);       // 32768 bf16

  float* outmu = (float*)d_out;
  float* outls = (float*)d_out + 3200000;

  const int egrid = (Etot + 255) / 256;

  // ---- CSR build (shared by all 3 convs) ----
  hipMemsetAsync(cnt, 0, 50000 * sizeof(int), stream);
  hist_k<<<egrid, 256, 0, stream>>>(ei, E0, Etot, cnt);
  scanA_k<<<(N + 1023) / 1024, 1024, 0, stream>>>(cnt, offs, bsums, N);
  scanB_k<<<1, 64, 0, stream>>>(bsums, (N + 1023) / 1024);
  scanC_k<<<(N + 256) / 256, 256, 0, stream>>>(offs, bsums, cursor, N, Etot);
  sort_k<<<egrid, 256, 0, stream>>>(ei, E0, Etot, cursor, srcs, dsts);

  // ---- weight/input packing for MFMA ----
  cvt_w_k<<<32, 256, 0, stream>>>(W1, Wmu, Wls, Bp1, Bp2);
  cvt_x_k<<<MT, 256, 0, stream>>>(x, Ap1);

  // ---- layer 1: GATConv(128 -> 4x64, concat) + bias + ReLU ----
  gemm1_mfma<<<MT, 256, 0, stream>>>(Ap1, Bp1, h1bf);
  alpha_k<4><<<(N * 4 + 255) / 256, 256, 0, stream>>>(h1bf, aS1, aD1, as1, ad1, N);
  logit1_k<<<egrid, 256, 0, stream>>>(srcs, dsts, as1, ad1, e1, Etot);
  gat_aggr1_k<<<(N + 3) / 4, 256, 0, stream>>>(offs, srcs, e1, h1bf, b1, Ap2, N, Etot);

  // ---- layers mu & logstd: GATConv(256 -> 1x64) + bias ----
  gemm2_mfma<<<MT, 256, 0, stream>>>(Ap2, Bp2, h2mu, h2ls);
  alpha_k<1><<<(N + 255) / 256, 256, 0, stream>>>(h2mu, aSmu, aDmu, as2m, ad2m, N);
  alpha_k<1><<<(N + 255) / 256, 256, 0, stream>>>(h2ls, aSls, aDls, as2l, ad2l, N);
  logit2_k<<<egrid, 256, 0, stream>>>(srcs, dsts, as2m, ad2m, as2l, ad2l, e2m, e2l, Etot);
  gat_aggr2_k<<<(N + 3) / 4, 256, 0, stream>>>(offs, srcs, e2m, e2l, h2mu, h2ls,
                                               bmu, bls, outmu, outls, N);
}

// Round 8
// 286.194 us; speedup vs baseline: 6.2719x; 1.1033x over previous
//
#include <hip/hip_runtime.h>
#include <hip/hip_bf16.h>

#define NNODES 50000
#define MT 3125              // NNODES / 16 row-tiles
typedef __hip_bfloat16 bf16;
typedef __attribute__((ext_vector_type(8))) short bf16x8;  // 8 bf16 (4 VGPRs)
typedef __attribute__((ext_vector_type(4))) float f32x4;   // 4 f32 acc

__device__ __forceinline__ void unpack2(unsigned w, float& lo, float& hi){
  lo = __uint_as_float(w << 16);
  hi = __uint_as_float(w & 0xffff0000u);
}
__device__ __forceinline__ short f2bf(float f){
  union { __hip_bfloat16 h; short s; } u; u.h = __float2bfloat16(f); return u.s;
}
__device__ __forceinline__ float lrelu(float v){ return v > 0.f ? v : 0.2f * v; }

// ---------------- pack x[50000,128] f32 -> A-fragment bf16 ----------------
__global__ __launch_bounds__(256)
void cvt_x_k(const float* __restrict__ x, bf16x8* __restrict__ Ap){
  int t = blockIdx.x * 256 + threadIdx.x;
  if (t >= MT * 256) return;
  int lane = t & 63;
  int kt   = (t >> 6) & 3;
  int rt   = t >> 8;
  const float* src = x + (size_t)(rt * 16 + (lane & 15)) * 128 + kt * 32 + (lane >> 4) * 8;
  float4 v0 = *(const float4*)src;
  float4 v1 = *(const float4*)(src + 4);
  bf16x8 o;
  o[0] = f2bf(v0.x); o[1] = f2bf(v0.y); o[2] = f2bf(v0.z); o[3] = f2bf(v0.w);
  o[4] = f2bf(v1.x); o[5] = f2bf(v1.y); o[6] = f2bf(v1.z); o[7] = f2bf(v1.w);
  Ap[t] = o;
}

// ---------------- pack weights -> B-fragment bf16 ----------------
__global__ __launch_bounds__(256)
void cvt_w_k(const float* __restrict__ W1, const float* __restrict__ Wmu,
             const float* __restrict__ Wls, bf16x8* __restrict__ Bp1,
             bf16x8* __restrict__ Bp2){
  int t = blockIdx.x * 256 + threadIdx.x;
  if (t < 4096){
    int lane = t & 63, ct = (t >> 6) & 15, kt = t >> 10;
    int k0 = kt * 32 + (lane >> 4) * 8, col = ct * 16 + (lane & 15);
    bf16x8 o;
    #pragma unroll
    for (int j = 0; j < 8; j++) o[j] = f2bf(W1[(size_t)(k0 + j) * 256 + col]);
    Bp1[t] = o;
  } else if (t < 8192){
    int u = t - 4096;
    int lane = u & 63, ct = (u >> 6) & 7, kt = u >> 9;
    int k0 = kt * 32 + (lane >> 4) * 8, col = ct * 16 + (lane & 15);
    const float* W = (col < 64) ? Wmu : Wls;
    int cc = col & 63;
    bf16x8 o;
    #pragma unroll
    for (int j = 0; j < 8; j++) o[j] = f2bf(W[(size_t)(k0 + j) * 64 + cc]);
    Bp2[u] = o;
  }
}

// ------- MFMA GEMM 1 + fused alpha: h1bf row-major, as1/ad1 from f32 acc -------
// wave w = head w (cols w*64..w*64+63)
__global__ __launch_bounds__(256)
void gemm1_mfma(const bf16x8* __restrict__ Ap, const bf16x8* __restrict__ Bp,
                const float* __restrict__ aS, const float* __restrict__ aD,
                bf16* __restrict__ Y, float* __restrict__ as1, float* __restrict__ ad1){
  int rt = blockIdx.x;
  int w = threadIdx.x >> 6, lane = threadIdx.x & 63;
  f32x4 z = {0.f, 0.f, 0.f, 0.f};
  f32x4 acc[4] = {z, z, z, z};
  for (int kt = 0; kt < 4; kt++){
    bf16x8 a = Ap[(size_t)(rt * 4 + kt) * 64 + lane];
    #pragma unroll
    for (int c = 0; c < 4; c++){
      bf16x8 b = Bp[(size_t)(kt * 16 + w * 4 + c) * 64 + lane];
      acc[c] = __builtin_amdgcn_mfma_f32_16x16x32_bf16(a, b, acc[c], 0, 0, 0);
    }
  }
  int row0 = rt * 16 + (lane >> 4) * 4;
  #pragma unroll
  for (int c = 0; c < 4; c++){
    int col = w * 64 + c * 16 + (lane & 15);
    #pragma unroll
    for (int i = 0; i < 4; i++)
      Y[(size_t)(row0 + i) * 256 + col] = __float2bfloat16(acc[c][i]);
  }
  // fused alpha: dot over head w's 64 cols, reduce across the 16-lane col groups
  float aSv[4], aDv[4];
  #pragma unroll
  for (int c = 0; c < 4; c++){
    int col = c * 16 + (lane & 15);
    aSv[c] = aS[w * 64 + col];
    aDv[c] = aD[w * 64 + col];
  }
  #pragma unroll
  for (int i = 0; i < 4; i++){
    float s1 = 0.f, s2 = 0.f;
    #pragma unroll
    for (int c = 0; c < 4; c++){
      s1 = fmaf(acc[c][i], aSv[c], s1);
      s2 = fmaf(acc[c][i], aDv[c], s2);
    }
    #pragma unroll
    for (int o = 1; o < 16; o <<= 1){
      s1 += __shfl_xor(s1, o);
      s2 += __shfl_xor(s2, o);
    }
    if ((lane & 15) == 0){
      int node = row0 + i;
      as1[node * 4 + w] = s1;
      ad1[node * 4 + w] = s2;
    }
  }
}

// ------- MFMA GEMM 2 + fused alpha: wave = (row-tile local, branch) -------
// block = 4 waves = 2 row-tiles x {mu, ls}; each wave owns all 64 cols of its branch
__global__ __launch_bounds__(256)
void gemm2_mfma(const bf16x8* __restrict__ Ap, const bf16x8* __restrict__ Bp,
                const float* __restrict__ aSmu, const float* __restrict__ aDmu,
                const float* __restrict__ aSls, const float* __restrict__ aDls,
                bf16* __restrict__ Ymu, bf16* __restrict__ Yls,
                float* __restrict__ as2m, float* __restrict__ ad2m,
                float* __restrict__ as2l, float* __restrict__ ad2l){
  int w = threadIdx.x >> 6, lane = threadIdx.x & 63;
  int rt = blockIdx.x * 2 + (w >> 1);
  if (rt >= MT) return;
  int br = w & 1;
  f32x4 z = {0.f, 0.f, 0.f, 0.f};
  f32x4 acc[4] = {z, z, z, z};
  for (int kt = 0; kt < 8; kt++){
    bf16x8 a = Ap[(size_t)(rt * 8 + kt) * 64 + lane];
    #pragma unroll
    for (int c = 0; c < 4; c++){
      bf16x8 b = Bp[(size_t)(kt * 8 + br * 4 + c) * 64 + lane];
      acc[c] = __builtin_amdgcn_mfma_f32_16x16x32_bf16(a, b, acc[c], 0, 0, 0);
    }
  }
  bf16* Y = br ? Yls : Ymu;
  const float* aS = br ? aSls : aSmu;
  const float* aD = br ? aDls : aDmu;
  float* asO = br ? as2l : as2m;
  float* adO = br ? ad2l : ad2m;
  int row0 = rt * 16 + (lane >> 4) * 4;
  #pragma unroll
  for (int c = 0; c < 4; c++){
    int col = c * 16 + (lane & 15);
    #pragma unroll
    for (int i = 0; i < 4; i++)
      Y[(size_t)(row0 + i) * 64 + col] = __float2bfloat16(acc[c][i]);
  }
  float aSv[4], aDv[4];
  #pragma unroll
  for (int c = 0; c < 4; c++){
    int col = c * 16 + (lane & 15);
    aSv[c] = aS[col];
    aDv[c] = aD[col];
  }
  #pragma unroll
  for (int i = 0; i < 4; i++){
    float s1 = 0.f, s2 = 0.f;
    #pragma unroll
    for (int c = 0; c < 4; c++){
      s1 = fmaf(acc[c][i], aSv[c], s1);
      s2 = fmaf(acc[c][i], aDv[c], s2);
    }
    #pragma unroll
    for (int o = 1; o < 16; o <<= 1){
      s1 += __shfl_xor(s1, o);
      s2 += __shfl_xor(s2, o);
    }
    if ((lane & 15) == 0){
      int node = row0 + i;
      asO[node] = s1;
      adO[node] = s2;
    }
  }
}

// ---------------- CSR build ----------------
__global__ __launch_bounds__(256)
void hist_k(const int* __restrict__ ei, int E0, int Etot, int* __restrict__ cnt){
  int e = blockIdx.x * 256 + threadIdx.x;
  if (e >= Etot) return;
  int d = (e < E0) ? ei[E0 + e] : e - E0;
  atomicAdd(&cnt[d], 1);
}

__global__ __launch_bounds__(1024)
void scanA_k(const int* __restrict__ cnt, int* __restrict__ offs,
             int* __restrict__ bsums, int n){
  __shared__ int buf[1024];
  int tid = threadIdx.x;
  int i = blockIdx.x * 1024 + tid;
  int v = (i < n) ? cnt[i] : 0;
  buf[tid] = v; __syncthreads();
  int acc = v;
  for (int off = 1; off < 1024; off <<= 1){
    int t = (tid >= off) ? buf[tid - off] : 0;
    __syncthreads();
    acc += t; buf[tid] = acc;
    __syncthreads();
  }
  if (i < n) offs[i] = acc - v;
  if (tid == 1023) bsums[blockIdx.x] = acc;
}

__global__ void scanB_k(int* __restrict__ bsums, int nb){
  int lane = threadIdx.x;
  int orig = (lane < nb) ? bsums[lane] : 0;
  int v = orig;
  #pragma unroll
  for (int o = 1; o < 64; o <<= 1){
    int t = __shfl_up(v, o);
    if (lane >= o) v += t;
  }
  if (lane < nb) bsums[lane] = v - orig;   // exclusive
}

__global__ __launch_bounds__(256)
void scanC_k(int* __restrict__ offs, const int* __restrict__ bsums,
             int* __restrict__ cursor, int n, int total){
  int i = blockIdx.x * 256 + threadIdx.x;
  if (i < n){
    int v = offs[i] + bsums[i >> 10];
    offs[i] = v;
    cursor[i] = v;
  }
  if (i == 0) offs[n] = total;
}

__global__ __launch_bounds__(256)
void sort_k(const int* __restrict__ ei, int E0, int Etot,
            int* __restrict__ cursor, int* __restrict__ srcs){
  int e = blockIdx.x * 256 + threadIdx.x;
  if (e >= Etot) return;
  int s, d;
  if (e < E0){ s = ei[e]; d = ei[E0 + e]; } else { s = d = e - E0; }
  int pos = atomicAdd(&cursor[d], 1);
  srcs[pos] = s;
}

// ------- fused aggregation, layer 1: one wave per node, logits on the fly -------
__global__ __launch_bounds__(256)
void gat_aggr1_k(const int* __restrict__ offs, const int* __restrict__ srcs,
                 const float* __restrict__ as, const float* __restrict__ ad,
                 const bf16* __restrict__ h, const float* __restrict__ b,
                 bf16x8* __restrict__ Ap2, int n){
  int node = blockIdx.x * 4 + (threadIdx.x >> 6);
  if (node >= n) return;
  int lane = threadIdx.x & 63;
  int beg = offs[node], end = offs[node + 1];
  // pass A/B: head = lane>>4, idx = lane&15
  int hA = lane >> 4;
  int iA = lane & 15;
  float adv = ad[node * 4 + hA];
  float mx = -1e30f;
  for (int j = beg + iA; j < end; j += 16)
    mx = fmaxf(mx, lrelu(as[srcs[j] * 4 + hA] + adv));
  #pragma unroll
  for (int o = 1; o < 16; o <<= 1) mx = fmaxf(mx, __shfl_xor(mx, o));
  float sm = 0.f;
  for (int j = beg + iA; j < end; j += 16)
    sm += __expf(lrelu(as[srcs[j] * 4 + hA] + adv) - mx);
  #pragma unroll
  for (int o = 1; o < 16; o <<= 1) sm += __shfl_xor(sm, o);
  float inv = 1.f / (sm + 1e-16f);
  // pass 2: slot = lane>>5, head = (lane>>3)&3, octet = lane&7
  int hP   = (lane >> 3) & 3;
  int oct  = lane & 7;
  int slot = lane >> 5;
  float mxP  = __shfl(mx, hP * 16);
  float invP = __shfl(inv, hP * 16);
  float advP = __shfl(adv, hP * 16);
  float acc[8];
  #pragma unroll
  for (int i = 0; i < 8; i++) acc[i] = 0.f;
  #pragma unroll 4
  for (int j0 = beg; j0 < end; j0 += 2){
    int j = j0 + slot;
    bool val = j < end;
    int s   = val ? srcs[j] : 0;
    float a = 0.f;
    if (val) a = __expf(lrelu(as[s * 4 + hP] + advP) - mxP) * invP;
    uint4 dw = *(const uint4*)(h + (size_t)s * 256 + hP * 64 + oct * 8);
    float lo, hi;
    unpack2(dw.x, lo, hi); acc[0] = fmaf(lo, a, acc[0]); acc[1] = fmaf(hi, a, acc[1]);
    unpack2(dw.y, lo, hi); acc[2] = fmaf(lo, a, acc[2]); acc[3] = fmaf(hi, a, acc[3]);
    unpack2(dw.z, lo, hi); acc[4] = fmaf(lo, a, acc[4]); acc[5] = fmaf(hi, a, acc[5]);
    unpack2(dw.w, lo, hi); acc[6] = fmaf(lo, a, acc[6]); acc[7] = fmaf(hi, a, acc[7]);
  }
  #pragma unroll
  for (int i = 0; i < 8; i++) acc[i] += __shfl_xor(acc[i], 32);
  if (lane < 32){
    bf16x8 o;
    #pragma unroll
    for (int i = 0; i < 8; i++){
      float vv = acc[i] + b[lane * 8 + i];
      o[i] = f2bf(vv > 0.f ? vv : 0.f);
    }
    int kt = lane >> 2, g = lane & 3;
    int rt = node >> 4, r = node & 15;
    Ap2[(size_t)(rt * 8 + kt) * 64 + g * 16 + r] = o;
  }
}

// ------- fused aggregation, mu & logstd: one wave per node, logits on the fly -------
__global__ __launch_bounds__(256)
void gat_aggr2_k(const int* __restrict__ offs, const int* __restrict__ srcs,
                 const float* __restrict__ as2m, const float* __restrict__ ad2m,
                 const float* __restrict__ as2l, const float* __restrict__ ad2l,
                 const bf16* __restrict__ hmu, const bf16* __restrict__ hls,
                 const float* __restrict__ bmu, const float* __restrict__ bls,
                 float* __restrict__ outmu, float* __restrict__ outls, int n){
  int node = blockIdx.x * 4 + (threadIdx.x >> 6);
  if (node >= n) return;
  int lane = threadIdx.x & 63;
  int beg = offs[node], end = offs[node + 1];
  // pass A/B: branch = lane>>5 (0 = mu, 1 = ls), idx = lane&31
  const float* asA = (lane >= 32) ? as2l : as2m;
  float adv = ((lane >= 32) ? ad2l : ad2m)[node];
  int iA = lane & 31;
  float mx = -1e30f;
  for (int j = beg + iA; j < end; j += 32)
    mx = fmaxf(mx, lrelu(asA[srcs[j]] + adv));
  #pragma unroll
  for (int o = 1; o < 32; o <<= 1) mx = fmaxf(mx, __shfl_xor(mx, o));
  float sm = 0.f;
  for (int j = beg + iA; j < end; j += 32)
    sm += __expf(lrelu(asA[srcs[j]] + adv) - mx);
  #pragma unroll
  for (int o = 1; o < 32; o <<= 1) sm += __shfl_xor(sm, o);
  float inv = 1.f / (sm + 1e-16f);
  // pass 2: slot = lane>>4, branch = (lane>>3)&1, octet = lane&7
  int br   = (lane >> 3) & 1;
  int oct  = lane & 7;
  int slot = lane >> 4;
  float mxP  = __shfl(mx, br * 32);
  float invP = __shfl(inv, br * 32);
  float advP = __shfl(adv, br * 32);
  const float* asP = br ? as2l : as2m;
  const bf16*  hP  = br ? hls : hmu;
  float acc[8];
  #pragma unroll
  for (int i = 0; i < 8; i++) acc[i] = 0.f;
  #pragma unroll 4
  for (int j0 = beg; j0 < end; j0 += 4){
    int j = j0 + slot;
    bool val = j < end;
    int s   = val ? srcs[j] : 0;
    float a = 0.f;
    if (val) a = __expf(lrelu(asP[s] + advP) - mxP) * invP;
    uint4 dw = *(const uint4*)(hP + (size_t)s * 64 + oct * 8);
    float lo, hi;
    unpack2(dw.x, lo, hi); acc[0] = fmaf(lo, a, acc[0]); acc[1] = fmaf(hi, a, acc[1]);
    unpack2(dw.y, lo, hi); acc[2] = fmaf(lo, a, acc[2]); acc[3] = fmaf(hi, a, acc[3]);
    unpack2(dw.z, lo, hi); acc[4] = fmaf(lo, a, acc[4]); acc[5] = fmaf(hi, a, acc[5]);
    unpack2(dw.w, lo, hi); acc[6] = fmaf(lo, a, acc[6]); acc[7] = fmaf(hi, a, acc[7]);
  }
  #pragma unroll
  for (int i = 0; i < 8; i++){
    acc[i] += __shfl_xor(acc[i], 16);
    acc[i] += __shfl_xor(acc[i], 32);
  }
  if (lane < 16){
    const float* bb = (lane >= 8) ? bls : bmu;
    float* out = (lane >= 8) ? outls : outmu;
    float v[8];
    #pragma unroll
    for (int i = 0; i < 8; i++) v[i] = acc[i] + bb[oct * 8 + i];
    float* op = out + (size_t)node * 64 + oct * 8;
    *(float4*)op       = make_float4(v[0], v[1], v[2], v[3]);
    *(float4*)(op + 4) = make_float4(v[4], v[5], v[6], v[7]);
  }
}

extern "C" void kernel_launch(void* const* d_in, const int* in_sizes, int n_in,
                              void* d_out, int out_size, void* d_ws, size_t ws_size,
                              hipStream_t stream){
  const float* x    = (const float*)d_in[0];
  const int*   ei   = (const int*)d_in[1];
  const float* W1   = (const float*)d_in[2];
  const float* aS1  = (const float*)d_in[3];
  const float* aD1  = (const float*)d_in[4];
  const float* b1   = (const float*)d_in[5];
  const float* Wmu  = (const float*)d_in[6];
  const float* aSmu = (const float*)d_in[7];
  const float* aDmu = (const float*)d_in[8];
  const float* bmu  = (const float*)d_in[9];
  const float* Wls  = (const float*)d_in[10];
  const float* aSls = (const float*)d_in[11];
  const float* aDls = (const float*)d_in[12];
  const float* bls  = (const float*)d_in[13];

  const int N    = NNODES;
  const int E0   = in_sizes[1] / 2;
  const int Etot = E0 + N;

  // ---- workspace layout (float-unit offsets; bf16x8 arrays 16B-aligned) ----
  float* ws = (float*)d_ws;
  bf16x8* Ap2  = (bf16x8*)(ws);                 // [0, 6.4M): layer-1 out, packed A-frag
  bf16*   h1bf = (bf16*)(ws + 6400000);         // [6.4M, 12.8M): 12.8M bf16 row-major
  bf16x8* Ap1  = (bf16x8*)(ws + 12800000);      // [12.8M, 16.0M): x packed
  bf16*   h2mu = (bf16*)(ws + 16000000);        // [16M, 17.6M): 3.2M bf16
  bf16*   h2ls = (bf16*)(ws + 17600000);        // [17.6M, 19.2M)
  float*  as1  = ws + 19200000;                 // 200K
  float*  ad1  = ws + 19400000;                 // 200K
  float*  as2m = ws + 19600000;                 // 50K each
  float*  ad2m = ws + 19650000;
  float*  as2l = ws + 19700000;
  float*  ad2l = ws + 19750000;
  int* cnt    = (int*)(ws + 19800000);          // 50K
  int* cursor = (int*)(ws + 19850000);          // 50K
  int* offs   = (int*)(ws + 19900000);          // 50001
  int* srcs   = (int*)(ws + 19950016);          // 850K
  int* bsums  = (int*)(ws + 20800016);          // 64
  bf16x8* Bp1 = (bf16x8*)(ws + 20800080);       // 32768 bf16 = 16384 floats
  bf16x8* Bp2 = (bf16x8*)(ws + 20816464);       // 32768 bf16

  float* outmu = (float*)d_out;
  float* outls = (float*)d_out + 3200000;

  const int egrid = (Etot + 255) / 256;

  // ---- CSR build (shared by all 3 convs) ----
  hipMemsetAsync(cnt, 0, 50000 * sizeof(int), stream);
  hist_k<<<egrid, 256, 0, stream>>>(ei, E0, Etot, cnt);
  scanA_k<<<(N + 1023) / 1024, 1024, 0, stream>>>(cnt, offs, bsums, N);
  scanB_k<<<1, 64, 0, stream>>>(bsums, (N + 1023) / 1024);
  scanC_k<<<(N + 256) / 256, 256, 0, stream>>>(offs, bsums, cursor, N, Etot);
  sort_k<<<egrid, 256, 0, stream>>>(ei, E0, Etot, cursor, srcs);

  // ---- weight/input packing for MFMA ----
  cvt_w_k<<<32, 256, 0, stream>>>(W1, Wmu, Wls, Bp1, Bp2);
  cvt_x_k<<<MT, 256, 0, stream>>>(x, Ap1);

  // ---- layer 1: GATConv(128 -> 4x64, concat) + bias + ReLU ----
  gemm1_mfma<<<MT, 256, 0, stream>>>(Ap1, Bp1, aS1, aD1, h1bf, as1, ad1);
  gat_aggr1_k<<<(N + 3) / 4, 256, 0, stream>>>(offs, srcs, as1, ad1, h1bf, b1, Ap2, N);

  // ---- layers mu & logstd: GATConv(256 -> 1x64) + bias ----
  gemm2_mfma<<<(MT + 1) / 2, 256, 0, stream>>>(Ap2, Bp2, aSmu, aDmu, aSls, aDls,
                                               h2mu, h2ls, as2m, ad2m, as2l, ad2l);
  gat_aggr2_k<<<(N + 3) / 4, 256, 0, stream>>>(offs, srcs, as2m, ad2m, as2l, ad2l,
                                               h2mu, h2ls, bmu, bls, outmu, outls, N);
}